// Round 12
// baseline (5998.112 us; speedup 1.0000x reference)
//
#include <hip/hip_runtime.h>

#define SEQ 512
#define BATCH 32
#define NTAG 12
#define STOP_TAG 11

static __device__ __forceinline__ float sigm(float x) {
  return 1.0f / (1.0f + __expf(-x));
}
static __device__ __forceinline__ float tanh_fast(float x) {
  // exact identity: tanh(x) = 1 - 2/(exp(2x)+1); error only from __expf ulp
  return 1.0f - 2.0f / (1.0f + __expf(2.0f * x));
}

// ---------------- embedding gather: x0[s*32+b][e] = emb[inputs[b][s]][e] ----------------
__global__ __launch_bounds__(64) void embed_kernel(const int* __restrict__ inputs,
                                                   const float* __restrict__ emb,
                                                   float* __restrict__ x0) {
  const int sb = blockIdx.x;          // s*32 + b
  const int s = sb >> 5, b = sb & 31;
  const int tok = inputs[b * SEQ + s];
  const float4* src = (const float4*)(emb + (size_t)tok * 256);
  float4* dst = (float4*)(x0 + (size_t)sb * 256);
  dst[threadIdx.x] = src[threadIdx.x];
}

// ---------------- fp32 GEMM, 128x128 tile, 8x8/thread: C = A[M][K] @ W[N][K]^T (+b1+b2) ----------------
// M, N multiples of 128; C row stride = ldc (>= N).
__global__ __launch_bounds__(256) void gemm128(const float* __restrict__ A,
                                               const float* __restrict__ W,
                                               const float* __restrict__ b1,
                                               const float* __restrict__ b2,
                                               float* __restrict__ C,
                                               int M, int N, int K, int ldc) {
  __shared__ float aT[8][132];
  __shared__ float wT[8][132];
  const int tid = threadIdx.x;
  const int bm = blockIdx.x * 128;
  const int bn = blockIdx.y * 128;
  const int tm = (tid >> 4) << 3;   // 0..120
  const int tn = (tid & 15) << 3;   // 0..120
  const int lr = tid >> 1;          // tile row 0..127
  const int lk = (tid & 1) << 2;    // k offset 0 or 4
  const float* __restrict__ aSrc = A + (size_t)(bm + lr) * K + lk;
  const float* __restrict__ wSrc = W + (size_t)(bn + lr) * K + lk;
  float acc[8][8] = {{0.f}};
  for (int k0 = 0; k0 < K; k0 += 8) {
    const float4 av = *(const float4*)(aSrc + k0);
    const float4 wv = *(const float4*)(wSrc + k0);
    __syncthreads();                // previous iter's LDS reads complete
    aT[lk + 0][lr] = av.x; aT[lk + 1][lr] = av.y; aT[lk + 2][lr] = av.z; aT[lk + 3][lr] = av.w;
    wT[lk + 0][lr] = wv.x; wT[lk + 1][lr] = wv.y; wT[lk + 2][lr] = wv.z; wT[lk + 3][lr] = wv.w;
    __syncthreads();
#pragma unroll
    for (int k = 0; k < 8; ++k) {
      const float4 a0 = *(const float4*)&aT[k][tm];
      const float4 a1 = *(const float4*)&aT[k][tm + 4];
      const float4 w0 = *(const float4*)&wT[k][tn];
      const float4 w1 = *(const float4*)&wT[k][tn + 4];
      const float a[8] = {a0.x, a0.y, a0.z, a0.w, a1.x, a1.y, a1.z, a1.w};
      const float w[8] = {w0.x, w0.y, w0.z, w0.w, w1.x, w1.y, w1.z, w1.w};
#pragma unroll
      for (int i = 0; i < 8; ++i)
#pragma unroll
        for (int j = 0; j < 8; ++j)
          acc[i][j] = fmaf(a[i], w[j], acc[i][j]);
    }
  }
  float bias[8];
#pragma unroll
  for (int j = 0; j < 8; ++j) {
    const int n = bn + tn + j;
    bias[j] = (b1 ? b1[n] : 0.f) + (b2 ? b2[n] : 0.f);
  }
#pragma unroll
  for (int i = 0; i < 8; ++i) {
    float* row = C + (size_t)(bm + tm + i) * ldc + bn + tn;
    *(float4*)(row) = make_float4(acc[i][0] + bias[0], acc[i][1] + bias[1],
                                  acc[i][2] + bias[2], acc[i][3] + bias[3]);
    *(float4*)(row + 4) = make_float4(acc[i][4] + bias[4], acc[i][5] + bias[5],
                                      acc[i][6] + bias[6], acc[i][7] + bias[7]);
  }
}

// ---------------- generic fp32 GEMM (64x64 tile) — only for the ragged N=12 feats GEMM ----------------
__global__ __launch_bounds__(256) void gemm_nt(const float* __restrict__ A,
                                               const float* __restrict__ W,
                                               const float* __restrict__ b1,
                                               const float* __restrict__ b2,
                                               float* __restrict__ C,
                                               int M, int N, int K, int ldc) {
  __shared__ float aT[16][68];
  __shared__ float wT[16][68];
  const int tid = threadIdx.x;
  const int bm = blockIdx.x * 64;
  const int bn = blockIdx.y * 64;
  const int tm = ((tid >> 4) & 15) << 2;
  const int tn = (tid & 15) << 2;
  const int lr = tid >> 2;
  const int lk = (tid & 3) << 2;
  const bool wok = (bn + lr) < N;
  float acc00 = 0.f, acc01 = 0.f, acc02 = 0.f, acc03 = 0.f;
  float acc10 = 0.f, acc11 = 0.f, acc12 = 0.f, acc13 = 0.f;
  float acc20 = 0.f, acc21 = 0.f, acc22 = 0.f, acc23 = 0.f;
  float acc30 = 0.f, acc31 = 0.f, acc32 = 0.f, acc33 = 0.f;
  for (int k0 = 0; k0 < K; k0 += 16) {
    float4 av = *(const float4*)(A + (size_t)(bm + lr) * K + k0 + lk);
    float4 wv = make_float4(0.f, 0.f, 0.f, 0.f);
    if (wok) wv = *(const float4*)(W + (size_t)(bn + lr) * K + k0 + lk);
    aT[lk + 0][lr] = av.x; aT[lk + 1][lr] = av.y; aT[lk + 2][lr] = av.z; aT[lk + 3][lr] = av.w;
    wT[lk + 0][lr] = wv.x; wT[lk + 1][lr] = wv.y; wT[lk + 2][lr] = wv.z; wT[lk + 3][lr] = wv.w;
    __syncthreads();
#pragma unroll
    for (int k = 0; k < 16; ++k) {
      float4 a4 = *(const float4*)&aT[k][tm];
      float4 w4 = *(const float4*)&wT[k][tn];
      acc00 += a4.x * w4.x; acc01 += a4.x * w4.y; acc02 += a4.x * w4.z; acc03 += a4.x * w4.w;
      acc10 += a4.y * w4.x; acc11 += a4.y * w4.y; acc12 += a4.y * w4.z; acc13 += a4.y * w4.w;
      acc20 += a4.z * w4.x; acc21 += a4.z * w4.y; acc22 += a4.z * w4.z; acc23 += a4.z * w4.w;
      acc30 += a4.w * w4.x; acc31 += a4.w * w4.y; acc32 += a4.w * w4.z; acc33 += a4.w * w4.w;
    }
    __syncthreads();
  }
  float r[4][4] = {{acc00, acc01, acc02, acc03},
                   {acc10, acc11, acc12, acc13},
                   {acc20, acc21, acc22, acc23},
                   {acc30, acc31, acc32, acc33}};
#pragma unroll
  for (int i = 0; i < 4; ++i) {
#pragma unroll
    for (int j = 0; j < 4; ++j) {
      int n = bn + tn + j;
      if (n < N) {
        float v = r[i][j];
        if (b1) v += b1[n];
        if (b2) v += b2[n];
        C[(size_t)(bm + tm + i) * ldc + n] = v;
      }
    }
  }
}

// ---------------- 4-way-split BiLSTM scan, XCC-claimed co-XCD placement ----------------
// grid = 256. Instead of assuming a bid->XCD mapping, each WG reads its REAL XCD via
// s_getreg(HW_REG_XCC_ID) and CAS-claims a (pair,quarter) slot with home-XCD preference:
// lin in [xcd*32, xcd*32+31] first (pairs xcd*8..xcd*8+7), linear probe wraps on
// imbalance. All 4 quarters of a pair land on ONE XCD (shared L2) when balanced; spilled
// pairs degrade to the LLC fallback path (slow, never wrong). Output is identical under
// any assignment -> deterministic. Poll mechanics are R8-verbatim (R9/R10: do not touch).
__global__ __launch_bounds__(256, 1) void lstm_scan(const float* __restrict__ pre_f,
                                                    const float* __restrict__ pre_b,
                                                    const float* __restrict__ whh_f,
                                                    const float* __restrict__ whh_b,
                                                    float* __restrict__ hs,   // [SEQ*32][512]
                                                    float* __restrict__ hx,   // [64][2][256], NaN-init
                                                    unsigned int* __restrict__ claim) { // [256], 0-init
  const int tid = threadIdx.x;
  __shared__ int s_lin;
  if (tid == 0) {
    // HW_REG_XCC_ID = 20, offset 0, width 4  ->  imm = 20 | (0<<6) | ((4-1)<<11) = 6164
    const unsigned xcd = __builtin_amdgcn_s_getreg(6164) & 7u;
    int lin = 0;
    for (int i = 0; i < 256; ++i) {
      const int cand = (int)((xcd * 32 + i) & 255);
      unsigned exp = 0u;
      if (__hip_atomic_compare_exchange_strong(&claim[cand], &exp, 1u,
            __ATOMIC_RELAXED, __ATOMIC_RELAXED, __HIP_MEMORY_SCOPE_AGENT)) {
        lin = cand;
        break;
      }
    }
    s_lin = lin;
  }
  __syncthreads();
  const int lin = s_lin;
  const int pair = lin >> 2;        // 0..63
  const int q = lin & 3;            // quarter
  const int dir = pair >> 5;
  const int b = pair & 31;
  const float* __restrict__ pre = dir ? pre_b : pre_f;
  const float* __restrict__ whh = dir ? whh_b : whh_f;
  const int u = tid & 63;
  const int col = (tid >> 6) * 256 + (q << 6) + u;
  float* hx_w = hx + pair * 512;    // [2][256]

  __shared__ float4 stage[8192];   // 128 KB staging, clobbered between rounds
  __shared__ float hbuf[2][256];
  __shared__ float zbuf[256];

  // ---- LDS bounce, round 0: k in [0,128) ----
  for (int it = 0; it < 32; ++it) {
    const int id = (it << 8) + tid;
    const int lc = id >> 5;          // local col 0..255
    const int g = id & 31;
    const int gcol = ((lc >> 6) << 8) + (q << 6) + (lc & 63);
    stage[(lc << 5) | (g ^ (lc & 31))] = *((const float4*)(whh + (size_t)gcol * 256) + g);
  }
  __syncthreads();
  float4 wv[64];
#pragma unroll
  for (int g = 0; g < 32; ++g)
    wv[g] = stage[(tid << 5) | (g ^ (tid & 31))];
  __syncthreads();
  // ---- round 1: k in [128,256) overwrites the staging buffer ----
  for (int it = 0; it < 32; ++it) {
    const int id = (it << 8) + tid;
    const int lc = id >> 5;
    const int g = id & 31;
    const int gcol = ((lc >> 6) << 8) + (q << 6) + (lc & 63);
    stage[(lc << 5) | (g ^ (lc & 31))] = *((const float4*)(whh + (size_t)gcol * 256) + 32 + g);
  }
  __syncthreads();
#pragma unroll
  for (int g = 0; g < 32; ++g)
    wv[32 + g] = stage[(tid << 5) | (g ^ (tid & 31))];

  hbuf[0][tid] = 0.0f;
  hbuf[1][tid] = 0.0f;
  float c_reg = 0.0f;               // thread tid<64 owns cell state of unit q*64+tid
  const int sfirst = dir ? (SEQ - 1) : 0;
  float p = pre[((size_t)(sfirst * BATCH) + b) * 1024 + col];
  __syncthreads();

  for (int t = 0; t < SEQ; ++t) {
    const int s = dir ? (SEQ - 1 - t) : t;
    float np = 0.0f;                // prefetch next step's pre
    if (t + 1 < SEQ) {
      const int sn = dir ? (s - 1) : (s + 1);
      np = pre[((size_t)(sn * BATCH) + b) * 1024 + col];
    }
    if (t > 0) {
      if (tid < 192) {              // waves 0-2: poll the 192 peer h values (self-tagged)
        const int pq = (q + 1 + (tid >> 6)) & 3;
        const int slot = (pq << 6) + (tid & 63);
        const float ef = 2.0f * (float)((t - 1) & 3);
        const float* addr = hx_w + ((t - 1) & 1) * 256 + slot;
        float v;
        int spin = 0;
        while (true) {
          if (spin < 16) {
            // L1-bypass, L2-served load (now genuinely XCD-local by claim construction)
            asm volatile("global_load_dword %0, %1, off sc0\n\t"
                         "s_waitcnt vmcnt(0)"
                         : "=v"(v) : "v"(addr));
          } else {
            // LLC fallback: guaranteed to observe the write-through store
            v = __hip_atomic_load(addr, __ATOMIC_RELAXED, __HIP_MEMORY_SCOPE_AGENT);
          }
          if (__builtin_fabsf(v - ef) <= 1.0f) break;   // NaN/stale-band rejected
          ++spin;
          if (spin > 4) __builtin_amdgcn_s_sleep(1);    // damp poll flood
        }
        hbuf[t & 1][slot] = v - ef;   // exact (Sterbenz)
      }
      __syncthreads();
    }
    // z[col] = pre + sum_k h[k] * whh[col][k]; 4-way acc split breaks the FMA chain
    float a0 = p, a1 = 0.f, a2 = 0.f, a3 = 0.f;
    const float4* hb = (const float4*)hbuf[t & 1];
#pragma unroll
    for (int g = 0; g < 64; ++g) {
      const float4 h4 = hb[g];      // LDS broadcast
      a0 = fmaf(h4.x, wv[g].x, a0);
      a1 = fmaf(h4.y, wv[g].y, a1);
      a2 = fmaf(h4.z, wv[g].z, a2);
      a3 = fmaf(h4.w, wv[g].w, a3);
    }
    zbuf[tid] = (a0 + a1) + (a2 + a3);
    __syncthreads();
    if (tid < 64) {                 // wave 0: gate combine for unit q*64+u
      const float zi = zbuf[u];
      const float zf = zbuf[64 + u];
      const float zg = zbuf[128 + u];
      const float zo = zbuf[192 + u];
      c_reg = sigm(zf) * c_reg + sigm(zi) * tanh_fast(zg);
      const float h = sigm(zo) * tanh_fast(c_reg);
      // exchange-critical store FIRST (leads the store queue)
      __hip_atomic_store(hx_w + (t & 1) * 256 + (q << 6) + u, h + 2.0f * (float)(t & 3),
                         __ATOMIC_RELAXED, __HIP_MEMORY_SCOPE_AGENT);
      hbuf[(t + 1) & 1][(q << 6) + u] = h;   // ordered before peers' reads by next poll-barrier
      hs[((size_t)(s * BATCH) + b) * 512 + dir * 256 + (q << 6) + u] = h;
    }
    // no trailing barrier: next iteration's poll-__syncthreads orders zbuf/hbuf reuse
    p = np;
  }
}

// ---------------- attention: per time-step s, scores over the batch dim ----------------
__global__ __launch_bounds__(256) void attention_kernel(const float* __restrict__ h1s,
                                                        float* __restrict__ att) {
  const int s = blockIdx.x;
  __shared__ float wl[32][512];   // w rows
  __shared__ float xT[512][36];   // x transposed
  __shared__ float sc[32][33];    // scores / weights
  const int tid = threadIdx.x;
#pragma unroll
  for (int r = 0; r < 16; ++r) {
    int flat = r * 1024 + tid * 4;
    int bb = flat >> 9;
    int d = flat & 511;
    float4 wv = *(const float4*)(att + ((size_t)(s * BATCH) + bb) * 1024 + d);
    *(float4*)&wl[bb][d] = wv;
    float4 xv = *(const float4*)(h1s + ((size_t)(s * BATCH) + bb) * 512 + d);
    xT[d + 0][bb] = xv.x; xT[d + 1][bb] = xv.y; xT[d + 2][bb] = xv.z; xT[d + 3][bb] = xv.w;
  }
  __syncthreads();
  {
    const int i = tid >> 3;
    const int j0 = (tid & 7) << 2;
    float a0 = 0.f, a1 = 0.f, a2 = 0.f, a3 = 0.f;
    for (int k = 0; k < 512; ++k) {
      float wv = wl[i][k];
      float4 x4 = *(const float4*)&xT[k][j0];
      a0 += wv * x4.x; a1 += wv * x4.y; a2 += wv * x4.z; a3 += wv * x4.w;
    }
    sc[i][j0 + 0] = a0; sc[i][j0 + 1] = a1; sc[i][j0 + 2] = a2; sc[i][j0 + 3] = a3;
  }
  __syncthreads();
  if (tid < 32) {
    float m = -3.4e38f;
    for (int j = 0; j < 32; ++j) m = fmaxf(m, sc[tid][j]);
    float sum = 0.f;
    for (int j = 0; j < 32; ++j) { float ev = __expf(sc[tid][j] - m); sc[tid][j] = ev; sum += ev; }
    float inv = 1.0f / sum;
    for (int j = 0; j < 32; ++j) sc[tid][j] *= inv;
  }
  __syncthreads();
  {
    const int i = tid >> 3;
    const int dq = tid & 7;
#pragma unroll
    for (int rep = 0; rep < 8; ++rep) {
      const int d0 = dq * 64 + rep * 8;
      float g0 = 0.f, g1 = 0.f, g2 = 0.f, g3 = 0.f, g4 = 0.f, g5 = 0.f, g6 = 0.f, g7 = 0.f;
      for (int j = 0; j < 32; ++j) {
        float wt = sc[i][j];
        g0 += wt * xT[d0 + 0][j]; g1 += wt * xT[d0 + 1][j];
        g2 += wt * xT[d0 + 2][j]; g3 += wt * xT[d0 + 3][j];
        g4 += wt * xT[d0 + 4][j]; g5 += wt * xT[d0 + 5][j];
        g6 += wt * xT[d0 + 6][j]; g7 += wt * xT[d0 + 7][j];
      }
      float* o = att + ((size_t)(s * BATCH) + i) * 1024 + 512 + d0;
      *(float4*)(o) = make_float4(g0, g1, g2, g3);
      *(float4*)(o + 4) = make_float4(g4, g5, g6, g7);
    }
  }
}

// ---------------- Viterbi decode: one block per batch element ----------------
__global__ __launch_bounds__(64) void viterbi_kernel(const float* __restrict__ feats,
                                                     const float* __restrict__ trans,
                                                     int* __restrict__ out) {
  const int b = blockIdx.x;
  __shared__ float tl[NTAG][NTAG];
  __shared__ float fv[2][NTAG];
  __shared__ unsigned char bp[SEQ][NTAG];
  const int tid = threadIdx.x;
  for (int i = tid; i < NTAG * NTAG; i += 64) tl[i / NTAG][i % NTAG] = trans[i];
  if (tid < NTAG) fv[0][tid] = (tid == 10) ? 0.f : -10000.f;
  __syncthreads();
  for (int t = 0; t < SEQ; ++t) {
    const int cur = t & 1;
    if (tid < NTAG) {
      float m = -3.4e38f;
      int arg = 0;
      for (int p = 0; p < NTAG; ++p) {
        float v = fv[cur][p] + tl[tid][p];
        if (v > m) { m = v; arg = p; }   // strict > == first-max (matches jnp.argmax)
      }
      bp[t][tid] = (unsigned char)arg;
      fv[cur ^ 1][tid] = m + feats[((size_t)t * BATCH + b) * NTAG + tid];
    }
    __syncthreads();
  }
  if (tid == 0) {
    float m = -3.4e38f;
    int tag = 0;
    for (int p = 0; p < NTAG; ++p) {
      float v = fv[0][p] + tl[STOP_TAG][p];
      if (v > m) { m = v; tag = p; }
    }
    for (int t = SEQ - 1; t >= 0; --t) {
      out[b * SEQ + t] = tag;
      tag = bp[t][tag];
    }
  }
}

// ---------------- launch ----------------
extern "C" void kernel_launch(void* const* d_in, const int* in_sizes, int n_in,
                              void* d_out, int out_size, void* d_ws, size_t ws_size,
                              hipStream_t stream) {
  const int* inputs = (const int*)d_in[0];
  const float* emb = (const float*)d_in[1];
  const float* w1f_ih = (const float*)d_in[2];
  const float* w1f_hh = (const float*)d_in[3];
  const float* b1f_ih = (const float*)d_in[4];
  const float* b1f_hh = (const float*)d_in[5];
  const float* w1b_ih = (const float*)d_in[6];
  const float* w1b_hh = (const float*)d_in[7];
  const float* b1b_ih = (const float*)d_in[8];
  const float* b1b_hh = (const float*)d_in[9];
  const float* attW = (const float*)d_in[10];
  const float* w2f_ih = (const float*)d_in[11];
  const float* w2f_hh = (const float*)d_in[12];
  const float* b2f_ih = (const float*)d_in[13];
  const float* b2f_hh = (const float*)d_in[14];
  const float* w2b_ih = (const float*)d_in[15];
  const float* w2b_hh = (const float*)d_in[16];
  const float* b2b_ih = (const float*)d_in[17];
  const float* b2b_hh = (const float*)d_in[18];
  const float* h2t_W = (const float*)d_in[19];
  const float* h2t_b = (const float*)d_in[20];
  const float* trans = (const float*)d_in[21];

  float* ws = (float*)d_ws;
  float* preF = ws;                         // 16,777,216 f
  float* preB = ws + 16777216;              // 16,777,216 f
  float* h1s  = ws + 33554432;              //  8,388,608 f (L1 hidden; reused as h2s)
  float* att  = ws + 41943040;              // 16,777,216 f ([w|g] concat)
  float* x0   = ws + 58720256;              //  4,194,304 f (embeddings; reused as feats)
  float* feats = x0;
  float* hx1  = ws + 62914560;              // 32,768 f (64 pairs x 2 parity x 256)
  float* hx2  = ws + 62947328;              // 32,768 f (second scan region)
  unsigned int* claim1 = (unsigned int*)(ws + 62980096);  // 256 u
  unsigned int* claim2 = (unsigned int*)(ws + 62980352);  // 256 u
  int* out = (int*)d_out;

  // NaN-init exchange regions (replay-safe; NaN fails all band tests); zero claim tables.
  hipMemsetAsync(hx1, 0xFF, 2 * 32768 * sizeof(float), stream);
  hipMemsetAsync(claim1, 0, 2 * 256 * sizeof(unsigned int), stream);
  embed_kernel<<<SEQ * BATCH, 64, 0, stream>>>(inputs, emb, x0);
  gemm128<<<dim3(128, 8), 256, 0, stream>>>(x0, w1f_ih, b1f_ih, b1f_hh, preF, 16384, 1024, 256, 1024);
  gemm128<<<dim3(128, 8), 256, 0, stream>>>(x0, w1b_ih, b1b_ih, b1b_hh, preB, 16384, 1024, 256, 1024);
  lstm_scan<<<256, 256, 0, stream>>>(preF, preB, w1f_hh, w1b_hh, h1s, hx1, claim1);
  gemm128<<<dim3(128, 4), 256, 0, stream>>>(h1s, attW, nullptr, nullptr, att, 16384, 512, 512, 1024);
  attention_kernel<<<SEQ, 256, 0, stream>>>(h1s, att);
  gemm128<<<dim3(128, 8), 256, 0, stream>>>(att, w2f_ih, b2f_ih, b2f_hh, preF, 16384, 1024, 1024, 1024);
  gemm128<<<dim3(128, 8), 256, 0, stream>>>(att, w2b_ih, b2b_ih, b2b_hh, preB, 16384, 1024, 1024, 1024);
  lstm_scan<<<256, 256, 0, stream>>>(preF, preB, w2f_hh, w2b_hh, h1s, hx2, claim2);
  gemm_nt<<<dim3(256, 1), 256, 0, stream>>>(h1s, h2t_W, h2t_b, nullptr, feats, 16384, 12, 512, 12);
  viterbi_kernel<<<BATCH, 64, 0, stream>>>(feats, trans, out);
}

// Round 14
// 5996.026 us; speedup vs baseline: 1.0003x; 1.0003x over previous
//
#include <hip/hip_runtime.h>

#define SEQ 512
#define BATCH 32
#define NTAG 12
#define STOP_TAG 11

static __device__ __forceinline__ float sigm(float x) {
  return 1.0f / (1.0f + __expf(-x));
}
static __device__ __forceinline__ float tanh_fast(float x) {
  // exact identity: tanh(x) = 1 - 2/(exp(2x)+1); error only from __expf ulp
  return 1.0f - 2.0f / (1.0f + __expf(2.0f * x));
}

// ---------------- embedding gather: x0[s*32+b][e] = emb[inputs[b][s]][e] ----------------
__global__ __launch_bounds__(64) void embed_kernel(const int* __restrict__ inputs,
                                                   const float* __restrict__ emb,
                                                   float* __restrict__ x0) {
  const int sb = blockIdx.x;          // s*32 + b
  const int s = sb >> 5, b = sb & 31;
  const int tok = inputs[b * SEQ + s];
  const float4* src = (const float4*)(emb + (size_t)tok * 256);
  float4* dst = (float4*)(x0 + (size_t)sb * 256);
  dst[threadIdx.x] = src[threadIdx.x];
}

// ---------------- fp32 GEMM, 128x128 tile, 8x8/thread, BK=16, swizzled wT ----------------
// C = A[M][K] @ W[N][K]^T (+b1+b2). M, N multiples of 128; C row stride = ldc.
// wT columns stored at p = j + ((j>>5)&3)*4 (max 139 -> row padded to 140): the 16 lane
// addresses of a wave's wT read land on start-banks {0,8,16,24,4,12,20,28,...} -> 2-way
// (free, m136) instead of 4-way conflict. R13 ERRATA: row was 136 -> OOB write corrupted
// the tile; 140 is the re-derived bound (j=127 -> p=139).
__global__ __launch_bounds__(256) void gemm128(const float* __restrict__ A,
                                               const float* __restrict__ W,
                                               const float* __restrict__ b1,
                                               const float* __restrict__ b2,
                                               float* __restrict__ C,
                                               int M, int N, int K, int ldc) {
  __shared__ float aT[16][132];
  __shared__ float wT[16][140];
  const int tid = threadIdx.x;
  const int bm = blockIdx.x * 128;
  const int bn = blockIdx.y * 128;
  const int tm = (tid >> 4) << 3;                 // 0..120
  const int tn = (tid & 15) << 3;                 // 0..120
  const int pn = tn + ((tn >> 5) & 3) * 4;        // swizzled read col (max 132)
  const int lr = tid >> 1;                        // tile row 0..127
  const int lk = (tid & 1) << 3;                  // k offset 0 or 8
  const int plr = lr + ((lr >> 5) & 3) * 4;       // swizzled write col (max 139)
  const float* __restrict__ aSrc = A + (size_t)(bm + lr) * K + lk;
  const float* __restrict__ wSrc = W + (size_t)(bn + lr) * K + lk;
  float acc[8][8] = {{0.f}};
  for (int k0 = 0; k0 < K; k0 += 16) {
    const float4 av0 = *(const float4*)(aSrc + k0);
    const float4 av1 = *(const float4*)(aSrc + k0 + 4);
    const float4 wv0 = *(const float4*)(wSrc + k0);
    const float4 wv1 = *(const float4*)(wSrc + k0 + 4);
    __syncthreads();                // previous iter's LDS reads complete
    aT[lk + 0][lr] = av0.x; aT[lk + 1][lr] = av0.y; aT[lk + 2][lr] = av0.z; aT[lk + 3][lr] = av0.w;
    aT[lk + 4][lr] = av1.x; aT[lk + 5][lr] = av1.y; aT[lk + 6][lr] = av1.z; aT[lk + 7][lr] = av1.w;
    wT[lk + 0][plr] = wv0.x; wT[lk + 1][plr] = wv0.y; wT[lk + 2][plr] = wv0.z; wT[lk + 3][plr] = wv0.w;
    wT[lk + 4][plr] = wv1.x; wT[lk + 5][plr] = wv1.y; wT[lk + 6][plr] = wv1.z; wT[lk + 7][plr] = wv1.w;
    __syncthreads();
#pragma unroll
    for (int k = 0; k < 16; ++k) {
      const float4 a0 = *(const float4*)&aT[k][tm];
      const float4 a1 = *(const float4*)&aT[k][tm + 4];
      const float4 w0 = *(const float4*)&wT[k][pn];
      const float4 w1 = *(const float4*)&wT[k][pn + 4];
      const float a[8] = {a0.x, a0.y, a0.z, a0.w, a1.x, a1.y, a1.z, a1.w};
      const float w[8] = {w0.x, w0.y, w0.z, w0.w, w1.x, w1.y, w1.z, w1.w};
#pragma unroll
      for (int i = 0; i < 8; ++i)
#pragma unroll
        for (int j = 0; j < 8; ++j)
          acc[i][j] = fmaf(a[i], w[j], acc[i][j]);
    }
  }
  float bias[8];
#pragma unroll
  for (int j = 0; j < 8; ++j) {
    const int n = bn + tn + j;
    bias[j] = (b1 ? b1[n] : 0.f) + (b2 ? b2[n] : 0.f);
  }
#pragma unroll
  for (int i = 0; i < 8; ++i) {
    float* row = C + (size_t)(bm + tm + i) * ldc + bn + tn;
    *(float4*)(row) = make_float4(acc[i][0] + bias[0], acc[i][1] + bias[1],
                                  acc[i][2] + bias[2], acc[i][3] + bias[3]);
    *(float4*)(row + 4) = make_float4(acc[i][4] + bias[4], acc[i][5] + bias[5],
                                      acc[i][6] + bias[6], acc[i][7] + bias[7]);
  }
}

// ---------------- generic fp32 GEMM (64x64 tile) — only for the ragged N=12 feats GEMM ----------------
__global__ __launch_bounds__(256) void gemm_nt(const float* __restrict__ A,
                                               const float* __restrict__ W,
                                               const float* __restrict__ b1,
                                               const float* __restrict__ b2,
                                               float* __restrict__ C,
                                               int M, int N, int K, int ldc) {
  __shared__ float aT[16][68];
  __shared__ float wT[16][68];
  const int tid = threadIdx.x;
  const int bm = blockIdx.x * 64;
  const int bn = blockIdx.y * 64;
  const int tm = ((tid >> 4) & 15) << 2;
  const int tn = (tid & 15) << 2;
  const int lr = tid >> 2;
  const int lk = (tid & 3) << 2;
  const bool wok = (bn + lr) < N;
  float acc00 = 0.f, acc01 = 0.f, acc02 = 0.f, acc03 = 0.f;
  float acc10 = 0.f, acc11 = 0.f, acc12 = 0.f, acc13 = 0.f;
  float acc20 = 0.f, acc21 = 0.f, acc22 = 0.f, acc23 = 0.f;
  float acc30 = 0.f, acc31 = 0.f, acc32 = 0.f, acc33 = 0.f;
  for (int k0 = 0; k0 < K; k0 += 16) {
    float4 av = *(const float4*)(A + (size_t)(bm + lr) * K + k0 + lk);
    float4 wv = make_float4(0.f, 0.f, 0.f, 0.f);
    if (wok) wv = *(const float4*)(W + (size_t)(bn + lr) * K + k0 + lk);
    aT[lk + 0][lr] = av.x; aT[lk + 1][lr] = av.y; aT[lk + 2][lr] = av.z; aT[lk + 3][lr] = av.w;
    wT[lk + 0][lr] = wv.x; wT[lk + 1][lr] = wv.y; wT[lk + 2][lr] = wv.z; wT[lk + 3][lr] = wv.w;
    __syncthreads();
#pragma unroll
    for (int k = 0; k < 16; ++k) {
      float4 a4 = *(const float4*)&aT[k][tm];
      float4 w4 = *(const float4*)&wT[k][tn];
      acc00 += a4.x * w4.x; acc01 += a4.x * w4.y; acc02 += a4.x * w4.z; acc03 += a4.x * w4.w;
      acc10 += a4.y * w4.x; acc11 += a4.y * w4.y; acc12 += a4.y * w4.z; acc13 += a4.y * w4.w;
      acc20 += a4.z * w4.x; acc21 += a4.z * w4.y; acc22 += a4.z * w4.z; acc23 += a4.z * w4.w;
      acc30 += a4.w * w4.x; acc31 += a4.w * w4.y; acc32 += a4.w * w4.z; acc33 += a4.w * w4.w;
    }
    __syncthreads();
  }
  float r[4][4] = {{acc00, acc01, acc02, acc03},
                   {acc10, acc11, acc12, acc13},
                   {acc20, acc21, acc22, acc23},
                   {acc30, acc31, acc32, acc33}};
#pragma unroll
  for (int i = 0; i < 4; ++i) {
#pragma unroll
    for (int j = 0; j < 4; ++j) {
      int n = bn + tn + j;
      if (n < N) {
        float v = r[i][j];
        if (b1) v += b1[n];
        if (b2) v += b2[n];
        C[(size_t)(bm + tm + i) * ldc + n] = v;
      }
    }
  }
}

// ---------------- 4-way-split BiLSTM scan, XCC-claimed co-XCD placement (R12 verbatim) ----------------
// FROZEN: R7-R12 tested 5 exchange variants; all land 4.5-5.2 us/step. R9/R10
// restructures regressed 30-60%. Do not touch the poll/store/prefetch structure.
__global__ __launch_bounds__(256, 1) void lstm_scan(const float* __restrict__ pre_f,
                                                    const float* __restrict__ pre_b,
                                                    const float* __restrict__ whh_f,
                                                    const float* __restrict__ whh_b,
                                                    float* __restrict__ hs,   // [SEQ*32][512]
                                                    float* __restrict__ hx,   // [64][2][256], NaN-init
                                                    unsigned int* __restrict__ claim) { // [256], 0-init
  const int tid = threadIdx.x;
  __shared__ int s_lin;
  if (tid == 0) {
    // HW_REG_XCC_ID = 20, offset 0, width 4  ->  imm = 20 | (0<<6) | ((4-1)<<11) = 6164
    const unsigned xcd = __builtin_amdgcn_s_getreg(6164) & 7u;
    int lin = 0;
    for (int i = 0; i < 256; ++i) {
      const int cand = (int)((xcd * 32 + i) & 255);
      unsigned exp = 0u;
      if (__hip_atomic_compare_exchange_strong(&claim[cand], &exp, 1u,
            __ATOMIC_RELAXED, __ATOMIC_RELAXED, __HIP_MEMORY_SCOPE_AGENT)) {
        lin = cand;
        break;
      }
    }
    s_lin = lin;
  }
  __syncthreads();
  const int lin = s_lin;
  const int pair = lin >> 2;        // 0..63
  const int q = lin & 3;            // quarter
  const int dir = pair >> 5;
  const int b = pair & 31;
  const float* __restrict__ pre = dir ? pre_b : pre_f;
  const float* __restrict__ whh = dir ? whh_b : whh_f;
  const int u = tid & 63;
  const int col = (tid >> 6) * 256 + (q << 6) + u;
  float* hx_w = hx + pair * 512;    // [2][256]

  __shared__ float4 stage[8192];   // 128 KB staging, clobbered between rounds
  __shared__ float hbuf[2][256];
  __shared__ float zbuf[256];

  // ---- LDS bounce, round 0: k in [0,128) ----
  for (int it = 0; it < 32; ++it) {
    const int id = (it << 8) + tid;
    const int lc = id >> 5;          // local col 0..255
    const int g = id & 31;
    const int gcol = ((lc >> 6) << 8) + (q << 6) + (lc & 63);
    stage[(lc << 5) | (g ^ (lc & 31))] = *((const float4*)(whh + (size_t)gcol * 256) + g);
  }
  __syncthreads();
  float4 wv[64];
#pragma unroll
  for (int g = 0; g < 32; ++g)
    wv[g] = stage[(tid << 5) | (g ^ (tid & 31))];
  __syncthreads();
  // ---- round 1: k in [128,256) overwrites the staging buffer ----
  for (int it = 0; it < 32; ++it) {
    const int id = (it << 8) + tid;
    const int lc = id >> 5;
    const int g = id & 31;
    const int gcol = ((lc >> 6) << 8) + (q << 6) + (lc & 63);
    stage[(lc << 5) | (g ^ (lc & 31))] = *((const float4*)(whh + (size_t)gcol * 256) + 32 + g);
  }
  __syncthreads();
#pragma unroll
  for (int g = 0; g < 32; ++g)
    wv[32 + g] = stage[(tid << 5) | (g ^ (tid & 31))];

  hbuf[0][tid] = 0.0f;
  hbuf[1][tid] = 0.0f;
  float c_reg = 0.0f;               // thread tid<64 owns cell state of unit q*64+tid
  const int sfirst = dir ? (SEQ - 1) : 0;
  float p = pre[((size_t)(sfirst * BATCH) + b) * 1024 + col];
  __syncthreads();

  for (int t = 0; t < SEQ; ++t) {
    const int s = dir ? (SEQ - 1 - t) : t;
    float np = 0.0f;                // prefetch next step's pre
    if (t + 1 < SEQ) {
      const int sn = dir ? (s - 1) : (s + 1);
      np = pre[((size_t)(sn * BATCH) + b) * 1024 + col];
    }
    if (t > 0) {
      if (tid < 192) {              // waves 0-2: poll the 192 peer h values (self-tagged)
        const int pq = (q + 1 + (tid >> 6)) & 3;
        const int slot = (pq << 6) + (tid & 63);
        const float ef = 2.0f * (float)((t - 1) & 3);
        const float* addr = hx_w + ((t - 1) & 1) * 256 + slot;
        float v;
        int spin = 0;
        while (true) {
          if (spin < 16) {
            // L1-bypass, L2-served load
            asm volatile("global_load_dword %0, %1, off sc0\n\t"
                         "s_waitcnt vmcnt(0)"
                         : "=v"(v) : "v"(addr));
          } else {
            // LLC fallback: guaranteed to observe the write-through store
            v = __hip_atomic_load(addr, __ATOMIC_RELAXED, __HIP_MEMORY_SCOPE_AGENT);
          }
          if (__builtin_fabsf(v - ef) <= 1.0f) break;   // NaN/stale-band rejected
          ++spin;
          if (spin > 4) __builtin_amdgcn_s_sleep(1);    // damp poll flood
        }
        hbuf[t & 1][slot] = v - ef;   // exact (Sterbenz)
      }
      __syncthreads();
    }
    // z[col] = pre + sum_k h[k] * whh[col][k]; 4-way acc split breaks the FMA chain
    float a0 = p, a1 = 0.f, a2 = 0.f, a3 = 0.f;
    const float4* hb = (const float4*)hbuf[t & 1];
#pragma unroll
    for (int g = 0; g < 64; ++g) {
      const float4 h4 = hb[g];      // LDS broadcast
      a0 = fmaf(h4.x, wv[g].x, a0);
      a1 = fmaf(h4.y, wv[g].y, a1);
      a2 = fmaf(h4.z, wv[g].z, a2);
      a3 = fmaf(h4.w, wv[g].w, a3);
    }
    zbuf[tid] = (a0 + a1) + (a2 + a3);
    __syncthreads();
    if (tid < 64) {                 // wave 0: gate combine for unit q*64+u
      const float zi = zbuf[u];
      const float zf = zbuf[64 + u];
      const float zg = zbuf[128 + u];
      const float zo = zbuf[192 + u];
      c_reg = sigm(zf) * c_reg + sigm(zi) * tanh_fast(zg);
      const float h = sigm(zo) * tanh_fast(c_reg);
      // exchange-critical store FIRST (leads the store queue)
      __hip_atomic_store(hx_w + (t & 1) * 256 + (q << 6) + u, h + 2.0f * (float)(t & 3),
                         __ATOMIC_RELAXED, __HIP_MEMORY_SCOPE_AGENT);
      hbuf[(t + 1) & 1][(q << 6) + u] = h;   // ordered before peers' reads by next poll-barrier
      hs[((size_t)(s * BATCH) + b) * 512 + dir * 256 + (q << 6) + u] = h;
    }
    // no trailing barrier: next iteration's poll-__syncthreads orders zbuf/hbuf reuse
    p = np;
  }
}

// ---------------- attention: per time-step s, scores over the batch dim ----------------
__global__ __launch_bounds__(256) void attention_kernel(const float* __restrict__ h1s,
                                                        float* __restrict__ att) {
  const int s = blockIdx.x;
  __shared__ float wl[32][512];   // w rows
  __shared__ float xT[512][36];   // x transposed
  __shared__ float sc[32][33];    // scores / weights
  const int tid = threadIdx.x;
#pragma unroll
  for (int r = 0; r < 16; ++r) {
    int flat = r * 1024 + tid * 4;
    int bb = flat >> 9;
    int d = flat & 511;
    float4 wv = *(const float4*)(att + ((size_t)(s * BATCH) + bb) * 1024 + d);
    *(float4*)&wl[bb][d] = wv;
    float4 xv = *(const float4*)(h1s + ((size_t)(s * BATCH) + bb) * 512 + d);
    xT[d + 0][bb] = xv.x; xT[d + 1][bb] = xv.y; xT[d + 2][bb] = xv.z; xT[d + 3][bb] = xv.w;
  }
  __syncthreads();
  {
    const int i = tid >> 3;
    const int j0 = (tid & 7) << 2;
    float a0 = 0.f, a1 = 0.f, a2 = 0.f, a3 = 0.f;
    for (int k = 0; k < 512; ++k) {
      float wv = wl[i][k];
      float4 x4 = *(const float4*)&xT[k][j0];
      a0 += wv * x4.x; a1 += wv * x4.y; a2 += wv * x4.z; a3 += wv * x4.w;
    }
    sc[i][j0 + 0] = a0; sc[i][j0 + 1] = a1; sc[i][j0 + 2] = a2; sc[i][j0 + 3] = a3;
  }
  __syncthreads();
  if (tid < 32) {
    float m = -3.4e38f;
    for (int j = 0; j < 32; ++j) m = fmaxf(m, sc[tid][j]);
    float sum = 0.f;
    for (int j = 0; j < 32; ++j) { float ev = __expf(sc[tid][j] - m); sc[tid][j] = ev; sum += ev; }
    float inv = 1.0f / sum;
    for (int j = 0; j < 32; ++j) sc[tid][j] *= inv;
  }
  __syncthreads();
  {
    const int i = tid >> 3;
    const int dq = tid & 7;
#pragma unroll
    for (int rep = 0; rep < 8; ++rep) {
      const int d0 = dq * 64 + rep * 8;
      float g0 = 0.f, g1 = 0.f, g2 = 0.f, g3 = 0.f, g4 = 0.f, g5 = 0.f, g6 = 0.f, g7 = 0.f;
      for (int j = 0; j < 32; ++j) {
        float wt = sc[i][j];
        g0 += wt * xT[d0 + 0][j]; g1 += wt * xT[d0 + 1][j];
        g2 += wt * xT[d0 + 2][j]; g3 += wt * xT[d0 + 3][j];
        g4 += wt * xT[d0 + 4][j]; g5 += wt * xT[d0 + 5][j];
        g6 += wt * xT[d0 + 6][j]; g7 += wt * xT[d0 + 7][j];
      }
      float* o = att + ((size_t)(s * BATCH) + i) * 1024 + 512 + d0;
      *(float4*)(o) = make_float4(g0, g1, g2, g3);
      *(float4*)(o + 4) = make_float4(g4, g5, g6, g7);
    }
  }
}

// ---------------- Viterbi decode: one block per batch element ----------------
__global__ __launch_bounds__(64) void viterbi_kernel(const float* __restrict__ feats,
                                                     const float* __restrict__ trans,
                                                     int* __restrict__ out) {
  const int b = blockIdx.x;
  __shared__ float tl[NTAG][NTAG];
  __shared__ float fv[2][NTAG];
  __shared__ unsigned char bp[SEQ][NTAG];
  const int tid = threadIdx.x;
  for (int i = tid; i < NTAG * NTAG; i += 64) tl[i / NTAG][i % NTAG] = trans[i];
  if (tid < NTAG) fv[0][tid] = (tid == 10) ? 0.f : -10000.f;
  __syncthreads();
  for (int t = 0; t < SEQ; ++t) {
    const int cur = t & 1;
    if (tid < NTAG) {
      float m = -3.4e38f;
      int arg = 0;
      for (int p = 0; p < NTAG; ++p) {
        float v = fv[cur][p] + tl[tid][p];
        if (v > m) { m = v; arg = p; }   // strict > == first-max (matches jnp.argmax)
      }
      bp[t][tid] = (unsigned char)arg;
      fv[cur ^ 1][tid] = m + feats[((size_t)t * BATCH + b) * NTAG + tid];
    }
    __syncthreads();
  }
  if (tid == 0) {
    float m = -3.4e38f;
    int tag = 0;
    for (int p = 0; p < NTAG; ++p) {
      float v = fv[0][p] + tl[STOP_TAG][p];
      if (v > m) { m = v; tag = p; }
    }
    for (int t = SEQ - 1; t >= 0; --t) {
      out[b * SEQ + t] = tag;
      tag = bp[t][tag];
    }
  }
}

// ---------------- launch ----------------
extern "C" void kernel_launch(void* const* d_in, const int* in_sizes, int n_in,
                              void* d_out, int out_size, void* d_ws, size_t ws_size,
                              hipStream_t stream) {
  const int* inputs = (const int*)d_in[0];
  const float* emb = (const float*)d_in[1];
  const float* w1f_ih = (const float*)d_in[2];
  const float* w1f_hh = (const float*)d_in[3];
  const float* b1f_ih = (const float*)d_in[4];
  const float* b1f_hh = (const float*)d_in[5];
  const float* w1b_ih = (const float*)d_in[6];
  const float* w1b_hh = (const float*)d_in[7];
  const float* b1b_ih = (const float*)d_in[8];
  const float* b1b_hh = (const float*)d_in[9];
  const float* attW = (const float*)d_in[10];
  const float* w2f_ih = (const float*)d_in[11];
  const float* w2f_hh = (const float*)d_in[12];
  const float* b2f_ih = (const float*)d_in[13];
  const float* b2f_hh = (const float*)d_in[14];
  const float* w2b_ih = (const float*)d_in[15];
  const float* w2b_hh = (const float*)d_in[16];
  const float* b2b_ih = (const float*)d_in[17];
  const float* b2b_hh = (const float*)d_in[18];
  const float* h2t_W = (const float*)d_in[19];
  const float* h2t_b = (const float*)d_in[20];
  const float* trans = (const float*)d_in[21];

  float* ws = (float*)d_ws;
  float* preF = ws;                         // 16,777,216 f
  float* preB = ws + 16777216;              // 16,777,216 f
  float* h1s  = ws + 33554432;              //  8,388,608 f (L1 hidden; reused as h2s)
  float* att  = ws + 41943040;              // 16,777,216 f ([w|g] concat)
  float* x0   = ws + 58720256;              //  4,194,304 f (embeddings; reused as feats)
  float* feats = x0;
  float* hx1  = ws + 62914560;              // 32,768 f (64 pairs x 2 parity x 256)
  float* hx2  = ws + 62947328;              // 32,768 f (second scan region)
  unsigned int* claim1 = (unsigned int*)(ws + 62980096);  // 256 u
  unsigned int* claim2 = (unsigned int*)(ws + 62980352);  // 256 u
  int* out = (int*)d_out;

  // NaN-init exchange regions (replay-safe; NaN fails all band tests); zero claim tables.
  hipMemsetAsync(hx1, 0xFF, 2 * 32768 * sizeof(float), stream);
  hipMemsetAsync(claim1, 0, 2 * 256 * sizeof(unsigned int), stream);
  embed_kernel<<<SEQ * BATCH, 64, 0, stream>>>(inputs, emb, x0);
  gemm128<<<dim3(128, 8), 256, 0, stream>>>(x0, w1f_ih, b1f_ih, b1f_hh, preF, 16384, 1024, 256, 1024);
  gemm128<<<dim3(128, 8), 256, 0, stream>>>(x0, w1b_ih, b1b_ih, b1b_hh, preB, 16384, 1024, 256, 1024);
  lstm_scan<<<256, 256, 0, stream>>>(preF, preB, w1f_hh, w1b_hh, h1s, hx1, claim1);
  gemm128<<<dim3(128, 4), 256, 0, stream>>>(h1s, attW, nullptr, nullptr, att, 16384, 512, 512, 1024);
  attention_kernel<<<SEQ, 256, 0, stream>>>(h1s, att);
  gemm128<<<dim3(128, 8), 256, 0, stream>>>(att, w2f_ih, b2f_ih, b2f_hh, preF, 16384, 1024, 1024, 1024);
  gemm128<<<dim3(128, 8), 256, 0, stream>>>(att, w2b_ih, b2b_ih, b2b_hh, preB, 16384, 1024, 1024, 1024);
  lstm_scan<<<256, 256, 0, stream>>>(preF, preB, w2f_hh, w2b_hh, h1s, hx2, claim2);
  gemm_nt<<<dim3(256, 1), 256, 0, stream>>>(h1s, h2t_W, h2t_b, nullptr, feats, 16384, 12, 512, 12);
  viterbi_kernel<<<BATCH, 64, 0, stream>>>(feats, trans, out);
}

// Round 16
// 5497.261 us; speedup vs baseline: 1.0911x; 1.0907x over previous
//
#include <hip/hip_runtime.h>

#define SEQ 512
#define BATCH 32
#define NTAG 12
#define STOP_TAG 11

typedef __attribute__((ext_vector_type(8))) short bs8;   // 8 bf16 (4 VGPRs)
typedef __attribute__((ext_vector_type(4))) float fx4;   // MFMA C/D

static __device__ __forceinline__ float sigm(float x) {
  return 1.0f / (1.0f + __expf(-x));
}
static __device__ __forceinline__ float tanh_fast(float x) {
  // exact identity: tanh(x) = 1 - 2/(exp(2x)+1); error only from __expf ulp
  return 1.0f - 2.0f / (1.0f + __expf(2.0f * x));
}
static __device__ __forceinline__ ushort bf16_rne(float x) {
  unsigned u = __float_as_uint(x);
  return (ushort)((u + 0x7FFFu + ((u >> 16) & 1u)) >> 16);
}

// ---------------- embedding gather: x0[s*32+b][e] = emb[inputs[b][s]][e] ----------------
__global__ __launch_bounds__(64) void embed_kernel(const int* __restrict__ inputs,
                                                   const float* __restrict__ emb,
                                                   float* __restrict__ x0) {
  const int sb = blockIdx.x;          // s*32 + b
  const int s = sb >> 5, b = sb & 31;
  const int tok = inputs[b * SEQ + s];
  const float4* src = (const float4*)(emb + (size_t)tok * 256);
  float4* dst = (float4*)(x0 + (size_t)sb * 256);
  dst[threadIdx.x] = src[threadIdx.x];
}

// ---------------- hi/lo bf16 split conversion: in -> hi (bf16 RNE), lo (bf16 of residual) ----------------
__global__ __launch_bounds__(256) void cvt_hilo(const float* __restrict__ in,
                                                ushort* __restrict__ hi,
                                                ushort* __restrict__ lo, int n4) {
  const int stride = gridDim.x * 256;
  for (int i = blockIdx.x * 256 + threadIdx.x; i < n4; i += stride) {
    float4 v = ((const float4*)in)[i];
    float vv[4] = {v.x, v.y, v.z, v.w};
    ushort h[4], l[4];
#pragma unroll
    for (int j = 0; j < 4; ++j) {
      ushort hb = bf16_rne(vv[j]);
      float hf = __uint_as_float(((unsigned)hb) << 16);
      h[j] = hb;
      l[j] = bf16_rne(vv[j] - hf);
    }
    ((ushort4*)hi)[i] = make_ushort4(h[0], h[1], h[2], h[3]);
    ((ushort4*)lo)[i] = make_ushort4(l[0], l[1], l[2], l[3]);
  }
}

// ---------------- hi/lo bf16 MFMA GEMM: C = (Ah+Al)@(Wh+Wl)^T + b1 + b2 ----------------
// 3-term split (AlWl dropped, ~2^-18 rel): fp32-class accuracy at bf16 MFMA rate.
// 128x128 tile, 4 waves (2x2 of 64x64), K-step 32, 16x16x32 bf16 MFMA.
// k-slot filling uses 8-consecutive-k per lane-quadrant for BOTH operands — correct for
// any HW k-map since A/B share the slot->k function (dot product is perm-invariant).
// C/D layout per m89: col = lane&15, row = 4*(lane>>4) + reg.
__global__ __launch_bounds__(256) void gemm_mfma(const ushort* __restrict__ Ah,
                                                 const ushort* __restrict__ Al,
                                                 const ushort* __restrict__ Wh,
                                                 const ushort* __restrict__ Wl,
                                                 const float* __restrict__ b1,
                                                 const float* __restrict__ b2,
                                                 float* __restrict__ C,
                                                 int M, int N, int K) {
  __shared__ ushort lAh[128 * 40];   // 128 rows x 32 k, padded to 40 (2-way banks)
  __shared__ ushort lAl[128 * 40];
  __shared__ ushort lWh[128 * 40];
  __shared__ ushort lWl[128 * 40];
  const int tid = threadIdx.x;
  const int bm = blockIdx.x * 128;
  const int bn = blockIdx.y * 128;
  const int w = tid >> 6, lane = tid & 63;
  const int wr = (w >> 1) * 64, wc = (w & 1) * 64;   // wave's 64x64 quadrant
  const int r16 = lane & 15, q = lane >> 4;
  const int srow = tid & 127, shalf = tid >> 7;       // staging: row, 16-ushort half
  const size_t aBase = (size_t)(bm + srow) * K + 16 * shalf;
  const size_t wBase = (size_t)(bn + srow) * K + 16 * shalf;
  const int ldst = srow * 40 + 16 * shalf;
  fx4 acc[4][4];
#pragma unroll
  for (int i = 0; i < 4; ++i)
#pragma unroll
    for (int j = 0; j < 4; ++j) {
      fx4 z = {0.f, 0.f, 0.f, 0.f};
      acc[i][j] = z;
    }
  for (int k0 = 0; k0 < K; k0 += 32) {
    const float4 ah0 = *(const float4*)(Ah + aBase + k0);
    const float4 ah1 = *(const float4*)(Ah + aBase + k0 + 8);
    const float4 al0 = *(const float4*)(Al + aBase + k0);
    const float4 al1 = *(const float4*)(Al + aBase + k0 + 8);
    const float4 wh0 = *(const float4*)(Wh + wBase + k0);
    const float4 wh1 = *(const float4*)(Wh + wBase + k0 + 8);
    const float4 wl0 = *(const float4*)(Wl + wBase + k0);
    const float4 wl1 = *(const float4*)(Wl + wBase + k0 + 8);
    __syncthreads();                 // previous iter's LDS reads complete
    *(float4*)&lAh[ldst] = ah0; *(float4*)&lAh[ldst + 8] = ah1;
    *(float4*)&lAl[ldst] = al0; *(float4*)&lAl[ldst + 8] = al1;
    *(float4*)&lWh[ldst] = wh0; *(float4*)&lWh[ldst + 8] = wh1;
    *(float4*)&lWl[ldst] = wl0; *(float4*)&lWl[ldst + 8] = wl1;
    __syncthreads();
    bs8 fah[4], fal[4], fwh[4], fwl[4];
#pragma unroll
    for (int i = 0; i < 4; ++i) {
      const int ao = (wr + 16 * i + r16) * 40 + 8 * q;
      fah[i] = *(const bs8*)&lAh[ao];
      fal[i] = *(const bs8*)&lAl[ao];
      const int wo = (wc + 16 * i + r16) * 40 + 8 * q;
      fwh[i] = *(const bs8*)&lWh[wo];
      fwl[i] = *(const bs8*)&lWl[wo];
    }
#pragma unroll
    for (int i = 0; i < 4; ++i)
#pragma unroll
      for (int j = 0; j < 4; ++j) {
        acc[i][j] = __builtin_amdgcn_mfma_f32_16x16x32_bf16(fah[i], fwh[j], acc[i][j], 0, 0, 0);
        acc[i][j] = __builtin_amdgcn_mfma_f32_16x16x32_bf16(fah[i], fwl[j], acc[i][j], 0, 0, 0);
        acc[i][j] = __builtin_amdgcn_mfma_f32_16x16x32_bf16(fal[i], fwh[j], acc[i][j], 0, 0, 0);
      }
  }
#pragma unroll
  for (int i = 0; i < 4; ++i)
#pragma unroll
    for (int j = 0; j < 4; ++j) {
      const int crow = bm + wr + 16 * i + 4 * q;
      const int ccol = bn + wc + 16 * j + r16;
      const float bias = b1[ccol] + b2[ccol];
#pragma unroll
      for (int r = 0; r < 4; ++r)
        C[(size_t)(crow + r) * N + ccol] = acc[i][j][r] + bias;
    }
}

// ---------------- fp32 GEMM, 128x128 tile, 8x8/thread, BK=16, swizzled wT ----------------
__global__ __launch_bounds__(256) void gemm128(const float* __restrict__ A,
                                               const float* __restrict__ W,
                                               const float* __restrict__ b1,
                                               const float* __restrict__ b2,
                                               float* __restrict__ C,
                                               int M, int N, int K, int ldc) {
  __shared__ float aT[16][132];
  __shared__ float wT[16][140];
  const int tid = threadIdx.x;
  const int bm = blockIdx.x * 128;
  const int bn = blockIdx.y * 128;
  const int tm = (tid >> 4) << 3;
  const int tn = (tid & 15) << 3;
  const int pn = tn + ((tn >> 5) & 3) * 4;
  const int lr = tid >> 1;
  const int lk = (tid & 1) << 3;
  const int plr = lr + ((lr >> 5) & 3) * 4;
  const float* __restrict__ aSrc = A + (size_t)(bm + lr) * K + lk;
  const float* __restrict__ wSrc = W + (size_t)(bn + lr) * K + lk;
  float acc[8][8] = {{0.f}};
  for (int k0 = 0; k0 < K; k0 += 16) {
    const float4 av0 = *(const float4*)(aSrc + k0);
    const float4 av1 = *(const float4*)(aSrc + k0 + 4);
    const float4 wv0 = *(const float4*)(wSrc + k0);
    const float4 wv1 = *(const float4*)(wSrc + k0 + 4);
    __syncthreads();
    aT[lk + 0][lr] = av0.x; aT[lk + 1][lr] = av0.y; aT[lk + 2][lr] = av0.z; aT[lk + 3][lr] = av0.w;
    aT[lk + 4][lr] = av1.x; aT[lk + 5][lr] = av1.y; aT[lk + 6][lr] = av1.z; aT[lk + 7][lr] = av1.w;
    wT[lk + 0][plr] = wv0.x; wT[lk + 1][plr] = wv0.y; wT[lk + 2][plr] = wv0.z; wT[lk + 3][plr] = wv0.w;
    wT[lk + 4][plr] = wv1.x; wT[lk + 5][plr] = wv1.y; wT[lk + 6][plr] = wv1.z; wT[lk + 7][plr] = wv1.w;
    __syncthreads();
#pragma unroll
    for (int k = 0; k < 16; ++k) {
      const float4 a0 = *(const float4*)&aT[k][tm];
      const float4 a1 = *(const float4*)&aT[k][tm + 4];
      const float4 w0 = *(const float4*)&wT[k][pn];
      const float4 w1 = *(const float4*)&wT[k][pn + 4];
      const float a[8] = {a0.x, a0.y, a0.z, a0.w, a1.x, a1.y, a1.z, a1.w};
      const float w[8] = {w0.x, w0.y, w0.z, w0.w, w1.x, w1.y, w1.z, w1.w};
#pragma unroll
      for (int i = 0; i < 8; ++i)
#pragma unroll
        for (int j = 0; j < 8; ++j)
          acc[i][j] = fmaf(a[i], w[j], acc[i][j]);
    }
  }
  float bias[8];
#pragma unroll
  for (int j = 0; j < 8; ++j) {
    const int n = bn + tn + j;
    bias[j] = (b1 ? b1[n] : 0.f) + (b2 ? b2[n] : 0.f);
  }
#pragma unroll
  for (int i = 0; i < 8; ++i) {
    float* row = C + (size_t)(bm + tm + i) * ldc + bn + tn;
    *(float4*)(row) = make_float4(acc[i][0] + bias[0], acc[i][1] + bias[1],
                                  acc[i][2] + bias[2], acc[i][3] + bias[3]);
    *(float4*)(row + 4) = make_float4(acc[i][4] + bias[4], acc[i][5] + bias[5],
                                      acc[i][6] + bias[6], acc[i][7] + bias[7]);
  }
}

// ---------------- generic fp32 GEMM (64x64 tile) — only for the ragged N=12 feats GEMM ----------------
__global__ __launch_bounds__(256) void gemm_nt(const float* __restrict__ A,
                                               const float* __restrict__ W,
                                               const float* __restrict__ b1,
                                               const float* __restrict__ b2,
                                               float* __restrict__ C,
                                               int M, int N, int K, int ldc) {
  __shared__ float aT[16][68];
  __shared__ float wT[16][68];
  const int tid = threadIdx.x;
  const int bm = blockIdx.x * 64;
  const int bn = blockIdx.y * 64;
  const int tm = ((tid >> 4) & 15) << 2;
  const int tn = (tid & 15) << 2;
  const int lr = tid >> 2;
  const int lk = (tid & 3) << 2;
  const bool wok = (bn + lr) < N;
  float acc00 = 0.f, acc01 = 0.f, acc02 = 0.f, acc03 = 0.f;
  float acc10 = 0.f, acc11 = 0.f, acc12 = 0.f, acc13 = 0.f;
  float acc20 = 0.f, acc21 = 0.f, acc22 = 0.f, acc23 = 0.f;
  float acc30 = 0.f, acc31 = 0.f, acc32 = 0.f, acc33 = 0.f;
  for (int k0 = 0; k0 < K; k0 += 16) {
    float4 av = *(const float4*)(A + (size_t)(bm + lr) * K + k0 + lk);
    float4 wv = make_float4(0.f, 0.f, 0.f, 0.f);
    if (wok) wv = *(const float4*)(W + (size_t)(bn + lr) * K + k0 + lk);
    aT[lk + 0][lr] = av.x; aT[lk + 1][lr] = av.y; aT[lk + 2][lr] = av.z; aT[lk + 3][lr] = av.w;
    wT[lk + 0][lr] = wv.x; wT[lk + 1][lr] = wv.y; wT[lk + 2][lr] = wv.z; wT[lk + 3][lr] = wv.w;
    __syncthreads();
#pragma unroll
    for (int k = 0; k < 16; ++k) {
      float4 a4 = *(const float4*)&aT[k][tm];
      float4 w4 = *(const float4*)&wT[k][tn];
      acc00 += a4.x * w4.x; acc01 += a4.x * w4.y; acc02 += a4.x * w4.z; acc03 += a4.x * w4.w;
      acc10 += a4.y * w4.x; acc11 += a4.y * w4.y; acc12 += a4.y * w4.z; acc13 += a4.y * w4.w;
      acc20 += a4.z * w4.x; acc21 += a4.z * w4.y; acc22 += a4.z * w4.z; acc23 += a4.z * w4.w;
      acc30 += a4.w * w4.x; acc31 += a4.w * w4.y; acc32 += a4.w * w4.z; acc33 += a4.w * w4.w;
    }
    __syncthreads();
  }
  float r[4][4] = {{acc00, acc01, acc02, acc03},
                   {acc10, acc11, acc12, acc13},
                   {acc20, acc21, acc22, acc23},
                   {acc30, acc31, acc32, acc33}};
#pragma unroll
  for (int i = 0; i < 4; ++i) {
#pragma unroll
    for (int j = 0; j < 4; ++j) {
      int n = bn + tn + j;
      if (n < N) {
        float v = r[i][j];
        if (b1) v += b1[n];
        if (b2) v += b2[n];
        C[(size_t)(bm + tm + i) * ldc + n] = v;
      }
    }
  }
}

// ---------------- 4-way-split BiLSTM scan, XCC-claimed co-XCD placement (FROZEN) ----------------
// R7-R12 tested 5 exchange variants; all land 4.5-5.2 us/step (cross-CU visibility floor).
// R9/R10 restructures regressed 30-60%. Do not touch.
__global__ __launch_bounds__(256, 1) void lstm_scan(const float* __restrict__ pre_f,
                                                    const float* __restrict__ pre_b,
                                                    const float* __restrict__ whh_f,
                                                    const float* __restrict__ whh_b,
                                                    float* __restrict__ hs,   // [SEQ*32][512]
                                                    float* __restrict__ hx,   // [64][2][256], NaN-init
                                                    unsigned int* __restrict__ claim) { // [256], 0-init
  const int tid = threadIdx.x;
  __shared__ int s_lin;
  if (tid == 0) {
    const unsigned xcd = __builtin_amdgcn_s_getreg(6164) & 7u;  // HW_REG_XCC_ID
    int lin = 0;
    for (int i = 0; i < 256; ++i) {
      const int cand = (int)((xcd * 32 + i) & 255);
      unsigned exp = 0u;
      if (__hip_atomic_compare_exchange_strong(&claim[cand], &exp, 1u,
            __ATOMIC_RELAXED, __ATOMIC_RELAXED, __HIP_MEMORY_SCOPE_AGENT)) {
        lin = cand;
        break;
      }
    }
    s_lin = lin;
  }
  __syncthreads();
  const int lin = s_lin;
  const int pair = lin >> 2;
  const int q = lin & 3;
  const int dir = pair >> 5;
  const int b = pair & 31;
  const float* __restrict__ pre = dir ? pre_b : pre_f;
  const float* __restrict__ whh = dir ? whh_b : whh_f;
  const int u = tid & 63;
  const int col = (tid >> 6) * 256 + (q << 6) + u;
  float* hx_w = hx + pair * 512;

  __shared__ float4 stage[8192];
  __shared__ float hbuf[2][256];
  __shared__ float zbuf[256];

  for (int it = 0; it < 32; ++it) {
    const int id = (it << 8) + tid;
    const int lc = id >> 5;
    const int g = id & 31;
    const int gcol = ((lc >> 6) << 8) + (q << 6) + (lc & 63);
    stage[(lc << 5) | (g ^ (lc & 31))] = *((const float4*)(whh + (size_t)gcol * 256) + g);
  }
  __syncthreads();
  float4 wv[64];
#pragma unroll
  for (int g = 0; g < 32; ++g)
    wv[g] = stage[(tid << 5) | (g ^ (tid & 31))];
  __syncthreads();
  for (int it = 0; it < 32; ++it) {
    const int id = (it << 8) + tid;
    const int lc = id >> 5;
    const int g = id & 31;
    const int gcol = ((lc >> 6) << 8) + (q << 6) + (lc & 63);
    stage[(lc << 5) | (g ^ (lc & 31))] = *((const float4*)(whh + (size_t)gcol * 256) + 32 + g);
  }
  __syncthreads();
#pragma unroll
  for (int g = 0; g < 32; ++g)
    wv[32 + g] = stage[(tid << 5) | (g ^ (tid & 31))];

  hbuf[0][tid] = 0.0f;
  hbuf[1][tid] = 0.0f;
  float c_reg = 0.0f;
  const int sfirst = dir ? (SEQ - 1) : 0;
  float p = pre[((size_t)(sfirst * BATCH) + b) * 1024 + col];
  __syncthreads();

  for (int t = 0; t < SEQ; ++t) {
    const int s = dir ? (SEQ - 1 - t) : t;
    float np = 0.0f;
    if (t + 1 < SEQ) {
      const int sn = dir ? (s - 1) : (s + 1);
      np = pre[((size_t)(sn * BATCH) + b) * 1024 + col];
    }
    if (t > 0) {
      if (tid < 192) {
        const int pq = (q + 1 + (tid >> 6)) & 3;
        const int slot = (pq << 6) + (tid & 63);
        const float ef = 2.0f * (float)((t - 1) & 3);
        const float* addr = hx_w + ((t - 1) & 1) * 256 + slot;
        float v;
        int spin = 0;
        while (true) {
          if (spin < 16) {
            asm volatile("global_load_dword %0, %1, off sc0\n\t"
                         "s_waitcnt vmcnt(0)"
                         : "=v"(v) : "v"(addr));
          } else {
            v = __hip_atomic_load(addr, __ATOMIC_RELAXED, __HIP_MEMORY_SCOPE_AGENT);
          }
          if (__builtin_fabsf(v - ef) <= 1.0f) break;
          ++spin;
          if (spin > 4) __builtin_amdgcn_s_sleep(1);
        }
        hbuf[t & 1][slot] = v - ef;
      }
      __syncthreads();
    }
    float a0 = p, a1 = 0.f, a2 = 0.f, a3 = 0.f;
    const float4* hb = (const float4*)hbuf[t & 1];
#pragma unroll
    for (int g = 0; g < 64; ++g) {
      const float4 h4 = hb[g];
      a0 = fmaf(h4.x, wv[g].x, a0);
      a1 = fmaf(h4.y, wv[g].y, a1);
      a2 = fmaf(h4.z, wv[g].z, a2);
      a3 = fmaf(h4.w, wv[g].w, a3);
    }
    zbuf[tid] = (a0 + a1) + (a2 + a3);
    __syncthreads();
    if (tid < 64) {
      const float zi = zbuf[u];
      const float zf = zbuf[64 + u];
      const float zg = zbuf[128 + u];
      const float zo = zbuf[192 + u];
      c_reg = sigm(zf) * c_reg + sigm(zi) * tanh_fast(zg);
      const float h = sigm(zo) * tanh_fast(c_reg);
      __hip_atomic_store(hx_w + (t & 1) * 256 + (q << 6) + u, h + 2.0f * (float)(t & 3),
                         __ATOMIC_RELAXED, __HIP_MEMORY_SCOPE_AGENT);
      hbuf[(t + 1) & 1][(q << 6) + u] = h;
      hs[((size_t)(s * BATCH) + b) * 512 + dir * 256 + (q << 6) + u] = h;
    }
    p = np;
  }
}

// ---------------- attention: per time-step s, scores over the batch dim ----------------
__global__ __launch_bounds__(256) void attention_kernel(const float* __restrict__ h1s,
                                                        float* __restrict__ att) {
  const int s = blockIdx.x;
  __shared__ float wl[32][512];
  __shared__ float xT[512][36];
  __shared__ float sc[32][33];
  const int tid = threadIdx.x;
#pragma unroll
  for (int r = 0; r < 16; ++r) {
    int flat = r * 1024 + tid * 4;
    int bb = flat >> 9;
    int d = flat & 511;
    float4 wv = *(const float4*)(att + ((size_t)(s * BATCH) + bb) * 1024 + d);
    *(float4*)&wl[bb][d] = wv;
    float4 xv = *(const float4*)(h1s + ((size_t)(s * BATCH) + bb) * 512 + d);
    xT[d + 0][bb] = xv.x; xT[d + 1][bb] = xv.y; xT[d + 2][bb] = xv.z; xT[d + 3][bb] = xv.w;
  }
  __syncthreads();
  {
    const int i = tid >> 3;
    const int j0 = (tid & 7) << 2;
    float a0 = 0.f, a1 = 0.f, a2 = 0.f, a3 = 0.f;
    for (int k = 0; k < 512; ++k) {
      float wv = wl[i][k];
      float4 x4 = *(const float4*)&xT[k][j0];
      a0 += wv * x4.x; a1 += wv * x4.y; a2 += wv * x4.z; a3 += wv * x4.w;
    }
    sc[i][j0 + 0] = a0; sc[i][j0 + 1] = a1; sc[i][j0 + 2] = a2; sc[i][j0 + 3] = a3;
  }
  __syncthreads();
  if (tid < 32) {
    float m = -3.4e38f;
    for (int j = 0; j < 32; ++j) m = fmaxf(m, sc[tid][j]);
    float sum = 0.f;
    for (int j = 0; j < 32; ++j) { float ev = __expf(sc[tid][j] - m); sc[tid][j] = ev; sum += ev; }
    float inv = 1.0f / sum;
    for (int j = 0; j < 32; ++j) sc[tid][j] *= inv;
  }
  __syncthreads();
  {
    const int i = tid >> 3;
    const int dq = tid & 7;
#pragma unroll
    for (int rep = 0; rep < 8; ++rep) {
      const int d0 = dq * 64 + rep * 8;
      float g0 = 0.f, g1 = 0.f, g2 = 0.f, g3 = 0.f, g4 = 0.f, g5 = 0.f, g6 = 0.f, g7 = 0.f;
      for (int j = 0; j < 32; ++j) {
        float wt = sc[i][j];
        g0 += wt * xT[d0 + 0][j]; g1 += wt * xT[d0 + 1][j];
        g2 += wt * xT[d0 + 2][j]; g3 += wt * xT[d0 + 3][j];
        g4 += wt * xT[d0 + 4][j]; g5 += wt * xT[d0 + 5][j];
        g6 += wt * xT[d0 + 6][j]; g7 += wt * xT[d0 + 7][j];
      }
      float* o = att + ((size_t)(s * BATCH) + i) * 1024 + 512 + d0;
      *(float4*)(o) = make_float4(g0, g1, g2, g3);
      *(float4*)(o + 4) = make_float4(g4, g5, g6, g7);
    }
  }
}

// ---------------- Viterbi decode: one block per batch element ----------------
__global__ __launch_bounds__(64) void viterbi_kernel(const float* __restrict__ feats,
                                                     const float* __restrict__ trans,
                                                     int* __restrict__ out) {
  const int b = blockIdx.x;
  __shared__ float tl[NTAG][NTAG];
  __shared__ float fv[2][NTAG];
  __shared__ unsigned char bp[SEQ][NTAG];
  const int tid = threadIdx.x;
  for (int i = tid; i < NTAG * NTAG; i += 64) tl[i / NTAG][i % NTAG] = trans[i];
  if (tid < NTAG) fv[0][tid] = (tid == 10) ? 0.f : -10000.f;
  __syncthreads();
  for (int t = 0; t < SEQ; ++t) {
    const int cur = t & 1;
    if (tid < NTAG) {
      float m = -3.4e38f;
      int arg = 0;
      for (int p = 0; p < NTAG; ++p) {
        float v = fv[cur][p] + tl[tid][p];
        if (v > m) { m = v; arg = p; }   // strict > == first-max (matches jnp.argmax)
      }
      bp[t][tid] = (unsigned char)arg;
      fv[cur ^ 1][tid] = m + feats[((size_t)t * BATCH + b) * NTAG + tid];
    }
    __syncthreads();
  }
  if (tid == 0) {
    float m = -3.4e38f;
    int tag = 0;
    for (int p = 0; p < NTAG; ++p) {
      float v = fv[0][p] + tl[STOP_TAG][p];
      if (v > m) { m = v; tag = p; }
    }
    for (int t = SEQ - 1; t >= 0; --t) {
      out[b * SEQ + t] = tag;
      tag = bp[t][tag];
    }
  }
}

// ---------------- launch ----------------
extern "C" void kernel_launch(void* const* d_in, const int* in_sizes, int n_in,
                              void* d_out, int out_size, void* d_ws, size_t ws_size,
                              hipStream_t stream) {
  const int* inputs = (const int*)d_in[0];
  const float* emb = (const float*)d_in[1];
  const float* w1f_ih = (const float*)d_in[2];
  const float* w1f_hh = (const float*)d_in[3];
  const float* b1f_ih = (const float*)d_in[4];
  const float* b1f_hh = (const float*)d_in[5];
  const float* w1b_ih = (const float*)d_in[6];
  const float* w1b_hh = (const float*)d_in[7];
  const float* b1b_ih = (const float*)d_in[8];
  const float* b1b_hh = (const float*)d_in[9];
  const float* attW = (const float*)d_in[10];
  const float* w2f_ih = (const float*)d_in[11];
  const float* w2f_hh = (const float*)d_in[12];
  const float* b2f_ih = (const float*)d_in[13];
  const float* b2f_hh = (const float*)d_in[14];
  const float* w2b_ih = (const float*)d_in[15];
  const float* w2b_hh = (const float*)d_in[16];
  const float* b2b_ih = (const float*)d_in[17];
  const float* b2b_hh = (const float*)d_in[18];
  const float* h2t_W = (const float*)d_in[19];
  const float* h2t_b = (const float*)d_in[20];
  const float* trans = (const float*)d_in[21];

  // Memory plan (FOOTPRINT IDENTICAL TO R14 — R15's +42 MB overflowed ws_size):
  //   preF: L1 preact fwd; later MFMA-GEMM#1 output (L2 preact fwd)
  //   preB: L1 preact bwd; DEAD after scan1 -> attl (bf16 lo of att) lives in first half
  //   h1s : L1 hidden;     DEAD after attention -> atth (bf16 hi);  scan2 output (h2s)
  //   att : [w|g];         DEAD after cvt -> MFMA-GEMM#2 output (L2 preact bwd)
  //   x0  : embeddings;    DEAD after L1 GEMMs -> w2 hi/lo (2M f);  feats (final)
  float* ws = (float*)d_ws;
  float* preF = ws;                         // 16,777,216 f
  float* preB = ws + 16777216;              // 16,777,216 f
  float* h1s  = ws + 33554432;              //  8,388,608 f
  float* att  = ws + 41943040;              // 16,777,216 f
  float* x0   = ws + 58720256;              //  4,194,304 f
  float* feats = x0;
  float* hx1  = ws + 62914560;              // 32,768 f
  float* hx2  = ws + 62947328;              // 32,768 f
  unsigned int* claim1 = (unsigned int*)(ws + 62980096);  // 256 u
  unsigned int* claim2 = (unsigned int*)(ws + 62980352);  // 256 u
  ushort* atth = (ushort*)h1s;              // 16,777,216 us (= full h1s region)
  ushort* attl = (ushort*)preB;             // 16,777,216 us (= first half of preB)
  ushort* w2fh = (ushort*)x0;               // 1,048,576 us each (x0 region, 2M f total)
  ushort* w2fl = (ushort*)(x0 + 524288);
  ushort* w2bh = (ushort*)(x0 + 1048576);
  ushort* w2bl = (ushort*)(x0 + 1572864);
  float* preB2 = att;                       // MFMA-GEMM#2 output region
  int* out = (int*)d_out;

  hipMemsetAsync(hx1, 0xFF, 2 * 32768 * sizeof(float), stream);
  hipMemsetAsync(claim1, 0, 2 * 256 * sizeof(unsigned int), stream);
  embed_kernel<<<SEQ * BATCH, 64, 0, stream>>>(inputs, emb, x0);
  gemm128<<<dim3(128, 8), 256, 0, stream>>>(x0, w1f_ih, b1f_ih, b1f_hh, preF, 16384, 1024, 256, 1024);
  gemm128<<<dim3(128, 8), 256, 0, stream>>>(x0, w1b_ih, b1b_ih, b1b_hh, preB, 16384, 1024, 256, 1024);
  lstm_scan<<<256, 256, 0, stream>>>(preF, preB, w1f_hh, w1b_hh, h1s, hx1, claim1);
  gemm128<<<dim3(128, 4), 256, 0, stream>>>(h1s, attW, nullptr, nullptr, att, 16384, 512, 512, 1024);
  attention_kernel<<<SEQ, 256, 0, stream>>>(h1s, att);
  // h1s, preB, x0 now dead -> stage bf16 hi/lo operands there
  cvt_hilo<<<4096, 256, 0, stream>>>(att, atth, attl, 4194304);
  cvt_hilo<<<512, 256, 0, stream>>>(w2f_ih, w2fh, w2fl, 262144);
  cvt_hilo<<<512, 256, 0, stream>>>(w2b_ih, w2bh, w2bl, 262144);
  // att fp32 now dead -> GEMM#2 writes there
  gemm_mfma<<<dim3(128, 8), 256, 0, stream>>>(atth, attl, w2fh, w2fl, b2f_ih, b2f_hh, preF, 16384, 1024, 1024);
  gemm_mfma<<<dim3(128, 8), 256, 0, stream>>>(atth, attl, w2bh, w2bl, b2b_ih, b2b_hh, preB2, 16384, 1024, 1024);
  lstm_scan<<<256, 256, 0, stream>>>(preF, preB2, w2f_hh, w2b_hh, h1s, hx2, claim2);
  gemm_nt<<<dim3(256, 1), 256, 0, stream>>>(h1s, h2t_W, h2t_b, nullptr, feats, 16384, 12, 512, 12);
  viterbi_kernel<<<BATCH, 64, 0, stream>>>(feats, trans, out);
}

// Round 17
// 5401.255 us; speedup vs baseline: 1.1105x; 1.0178x over previous
//
#include <hip/hip_runtime.h>

#define SEQ 512
#define BATCH 32
#define NTAG 12
#define STOP_TAG 11

typedef __attribute__((ext_vector_type(8))) short bs8;   // 8 bf16 (4 VGPRs)
typedef __attribute__((ext_vector_type(4))) float fx4;   // MFMA C/D

static __device__ __forceinline__ float sigm(float x) {
  return 1.0f / (1.0f + __expf(-x));
}
static __device__ __forceinline__ float tanh_fast(float x) {
  // exact identity: tanh(x) = 1 - 2/(exp(2x)+1); error only from __expf ulp
  return 1.0f - 2.0f / (1.0f + __expf(2.0f * x));
}
static __device__ __forceinline__ ushort bf16_rne(float x) {
  unsigned u = __float_as_uint(x);
  return (ushort)((u + 0x7FFFu + ((u >> 16) & 1u)) >> 16);
}

// ---------------- embedding gather: x0[s*32+b][e] = emb[inputs[b][s]][e] ----------------
__global__ __launch_bounds__(64) void embed_kernel(const int* __restrict__ inputs,
                                                   const float* __restrict__ emb,
                                                   float* __restrict__ x0) {
  const int sb = blockIdx.x;          // s*32 + b
  const int s = sb >> 5, b = sb & 31;
  const int tok = inputs[b * SEQ + s];
  const float4* src = (const float4*)(emb + (size_t)tok * 256);
  float4* dst = (float4*)(x0 + (size_t)sb * 256);
  dst[threadIdx.x] = src[threadIdx.x];
}

// ---------------- hi/lo bf16 split conversion: in -> hi (bf16 RNE), lo (bf16 of residual) ----------------
__global__ __launch_bounds__(256) void cvt_hilo(const float* __restrict__ in,
                                                ushort* __restrict__ hi,
                                                ushort* __restrict__ lo, int n4) {
  const int stride = gridDim.x * 256;
  for (int i = blockIdx.x * 256 + threadIdx.x; i < n4; i += stride) {
    float4 v = ((const float4*)in)[i];
    float vv[4] = {v.x, v.y, v.z, v.w};
    ushort h[4], l[4];
#pragma unroll
    for (int j = 0; j < 4; ++j) {
      ushort hb = bf16_rne(vv[j]);
      float hf = __uint_as_float(((unsigned)hb) << 16);
      h[j] = hb;
      l[j] = bf16_rne(vv[j] - hf);
    }
    ((ushort4*)hi)[i] = make_ushort4(h[0], h[1], h[2], h[3]);
    ((ushort4*)lo)[i] = make_ushort4(l[0], l[1], l[2], l[3]);
  }
}

// ---------------- hi/lo bf16 MFMA GEMM: C = (Ah+Al)@(Wh+Wl)^T (+b1+b2) ----------------
// 3-term split (AlWl dropped, ~2^-18 rel): fp32-class accuracy at bf16 MFMA rate.
// 128x128 tile, 4 waves (2x2 of 64x64), K-step 32, 16x16x32 bf16 MFMA.
// k-slot filling uses 8-consecutive-k per lane-quadrant for BOTH operands — correct for
// any HW k-map since A/B share the slot->k function (dot product is perm-invariant).
// C/D layout per m89: col = lane&15, row = 4*(lane>>4) + reg. C row stride = ldc.
__global__ __launch_bounds__(256) void gemm_mfma(const ushort* __restrict__ Ah,
                                                 const ushort* __restrict__ Al,
                                                 const ushort* __restrict__ Wh,
                                                 const ushort* __restrict__ Wl,
                                                 const float* __restrict__ b1,
                                                 const float* __restrict__ b2,
                                                 float* __restrict__ C,
                                                 int M, int N, int K, int ldc) {
  __shared__ ushort lAh[128 * 40];   // 128 rows x 32 k, padded to 40 (2-way banks)
  __shared__ ushort lAl[128 * 40];
  __shared__ ushort lWh[128 * 40];
  __shared__ ushort lWl[128 * 40];
  const int tid = threadIdx.x;
  const int bm = blockIdx.x * 128;
  const int bn = blockIdx.y * 128;
  const int w = tid >> 6, lane = tid & 63;
  const int wr = (w >> 1) * 64, wc = (w & 1) * 64;   // wave's 64x64 quadrant
  const int r16 = lane & 15, q = lane >> 4;
  const int srow = tid & 127, shalf = tid >> 7;       // staging: row, 16-ushort half
  const size_t aBase = (size_t)(bm + srow) * K + 16 * shalf;
  const size_t wBase = (size_t)(bn + srow) * K + 16 * shalf;
  const int ldst = srow * 40 + 16 * shalf;
  fx4 acc[4][4];
#pragma unroll
  for (int i = 0; i < 4; ++i)
#pragma unroll
    for (int j = 0; j < 4; ++j) {
      fx4 z = {0.f, 0.f, 0.f, 0.f};
      acc[i][j] = z;
    }
  for (int k0 = 0; k0 < K; k0 += 32) {
    const float4 ah0 = *(const float4*)(Ah + aBase + k0);
    const float4 ah1 = *(const float4*)(Ah + aBase + k0 + 8);
    const float4 al0 = *(const float4*)(Al + aBase + k0);
    const float4 al1 = *(const float4*)(Al + aBase + k0 + 8);
    const float4 wh0 = *(const float4*)(Wh + wBase + k0);
    const float4 wh1 = *(const float4*)(Wh + wBase + k0 + 8);
    const float4 wl0 = *(const float4*)(Wl + wBase + k0);
    const float4 wl1 = *(const float4*)(Wl + wBase + k0 + 8);
    __syncthreads();                 // previous iter's LDS reads complete
    *(float4*)&lAh[ldst] = ah0; *(float4*)&lAh[ldst + 8] = ah1;
    *(float4*)&lAl[ldst] = al0; *(float4*)&lAl[ldst + 8] = al1;
    *(float4*)&lWh[ldst] = wh0; *(float4*)&lWh[ldst + 8] = wh1;
    *(float4*)&lWl[ldst] = wl0; *(float4*)&lWl[ldst + 8] = wl1;
    __syncthreads();
    bs8 fah[4], fal[4], fwh[4], fwl[4];
#pragma unroll
    for (int i = 0; i < 4; ++i) {
      const int ao = (wr + 16 * i + r16) * 40 + 8 * q;
      fah[i] = *(const bs8*)&lAh[ao];
      fal[i] = *(const bs8*)&lAl[ao];
      const int wo = (wc + 16 * i + r16) * 40 + 8 * q;
      fwh[i] = *(const bs8*)&lWh[wo];
      fwl[i] = *(const bs8*)&lWl[wo];
    }
#pragma unroll
    for (int i = 0; i < 4; ++i)
#pragma unroll
      for (int j = 0; j < 4; ++j) {
        acc[i][j] = __builtin_amdgcn_mfma_f32_16x16x32_bf16(fah[i], fwh[j], acc[i][j], 0, 0, 0);
        acc[i][j] = __builtin_amdgcn_mfma_f32_16x16x32_bf16(fah[i], fwl[j], acc[i][j], 0, 0, 0);
        acc[i][j] = __builtin_amdgcn_mfma_f32_16x16x32_bf16(fal[i], fwh[j], acc[i][j], 0, 0, 0);
      }
  }
#pragma unroll
  for (int i = 0; i < 4; ++i)
#pragma unroll
    for (int j = 0; j < 4; ++j) {
      const int crow = bm + wr + 16 * i + 4 * q;
      const int ccol = bn + wc + 16 * j + r16;
      const float bias = (b1 ? b1[ccol] : 0.f) + (b2 ? b2[ccol] : 0.f);
#pragma unroll
      for (int r = 0; r < 4; ++r)
        C[(size_t)(crow + r) * ldc + ccol] = acc[i][j][r] + bias;
    }
}

// ---------------- generic fp32 GEMM (64x64 tile) — only for the ragged N=12 feats GEMM ----------------
__global__ __launch_bounds__(256) void gemm_nt(const float* __restrict__ A,
                                               const float* __restrict__ W,
                                               const float* __restrict__ b1,
                                               const float* __restrict__ b2,
                                               float* __restrict__ C,
                                               int M, int N, int K, int ldc) {
  __shared__ float aT[16][68];
  __shared__ float wT[16][68];
  const int tid = threadIdx.x;
  const int bm = blockIdx.x * 64;
  const int bn = blockIdx.y * 64;
  const int tm = ((tid >> 4) & 15) << 2;
  const int tn = (tid & 15) << 2;
  const int lr = tid >> 2;
  const int lk = (tid & 3) << 2;
  const bool wok = (bn + lr) < N;
  float acc00 = 0.f, acc01 = 0.f, acc02 = 0.f, acc03 = 0.f;
  float acc10 = 0.f, acc11 = 0.f, acc12 = 0.f, acc13 = 0.f;
  float acc20 = 0.f, acc21 = 0.f, acc22 = 0.f, acc23 = 0.f;
  float acc30 = 0.f, acc31 = 0.f, acc32 = 0.f, acc33 = 0.f;
  for (int k0 = 0; k0 < K; k0 += 16) {
    float4 av = *(const float4*)(A + (size_t)(bm + lr) * K + k0 + lk);
    float4 wv = make_float4(0.f, 0.f, 0.f, 0.f);
    if (wok) wv = *(const float4*)(W + (size_t)(bn + lr) * K + k0 + lk);
    aT[lk + 0][lr] = av.x; aT[lk + 1][lr] = av.y; aT[lk + 2][lr] = av.z; aT[lk + 3][lr] = av.w;
    wT[lk + 0][lr] = wv.x; wT[lk + 1][lr] = wv.y; wT[lk + 2][lr] = wv.z; wT[lk + 3][lr] = wv.w;
    __syncthreads();
#pragma unroll
    for (int k = 0; k < 16; ++k) {
      float4 a4 = *(const float4*)&aT[k][tm];
      float4 w4 = *(const float4*)&wT[k][tn];
      acc00 += a4.x * w4.x; acc01 += a4.x * w4.y; acc02 += a4.x * w4.z; acc03 += a4.x * w4.w;
      acc10 += a4.y * w4.x; acc11 += a4.y * w4.y; acc12 += a4.y * w4.z; acc13 += a4.y * w4.w;
      acc20 += a4.z * w4.x; acc21 += a4.z * w4.y; acc22 += a4.z * w4.z; acc23 += a4.z * w4.w;
      acc30 += a4.w * w4.x; acc31 += a4.w * w4.y; acc32 += a4.w * w4.z; acc33 += a4.w * w4.w;
    }
    __syncthreads();
  }
  float r[4][4] = {{acc00, acc01, acc02, acc03},
                   {acc10, acc11, acc12, acc13},
                   {acc20, acc21, acc22, acc23},
                   {acc30, acc31, acc32, acc33}};
#pragma unroll
  for (int i = 0; i < 4; ++i) {
#pragma unroll
    for (int j = 0; j < 4; ++j) {
      int n = bn + tn + j;
      if (n < N) {
        float v = r[i][j];
        if (b1) v += b1[n];
        if (b2) v += b2[n];
        C[(size_t)(bm + tm + i) * ldc + n] = v;
      }
    }
  }
}

// ---------------- 4-way-split BiLSTM scan, XCC-claimed co-XCD placement (FROZEN) ----------------
// R7-R12 tested 5 exchange variants; all land 4.5-5.2 us/step (cross-CU visibility floor).
// R9/R10 restructures regressed 30-60%. Do not touch.
__global__ __launch_bounds__(256, 1) void lstm_scan(const float* __restrict__ pre_f,
                                                    const float* __restrict__ pre_b,
                                                    const float* __restrict__ whh_f,
                                                    const float* __restrict__ whh_b,
                                                    float* __restrict__ hs,   // [SEQ*32][512]
                                                    float* __restrict__ hx,   // [64][2][256], NaN-init
                                                    unsigned int* __restrict__ claim) { // [256], 0-init
  const int tid = threadIdx.x;
  __shared__ int s_lin;
  if (tid == 0) {
    const unsigned xcd = __builtin_amdgcn_s_getreg(6164) & 7u;  // HW_REG_XCC_ID
    int lin = 0;
    for (int i = 0; i < 256; ++i) {
      const int cand = (int)((xcd * 32 + i) & 255);
      unsigned exp = 0u;
      if (__hip_atomic_compare_exchange_strong(&claim[cand], &exp, 1u,
            __ATOMIC_RELAXED, __ATOMIC_RELAXED, __HIP_MEMORY_SCOPE_AGENT)) {
        lin = cand;
        break;
      }
    }
    s_lin = lin;
  }
  __syncthreads();
  const int lin = s_lin;
  const int pair = lin >> 2;
  const int q = lin & 3;
  const int dir = pair >> 5;
  const int b = pair & 31;
  const float* __restrict__ pre = dir ? pre_b : pre_f;
  const float* __restrict__ whh = dir ? whh_b : whh_f;
  const int u = tid & 63;
  const int col = (tid >> 6) * 256 + (q << 6) + u;
  float* hx_w = hx + pair * 512;

  __shared__ float4 stage[8192];
  __shared__ float hbuf[2][256];
  __shared__ float zbuf[256];

  for (int it = 0; it < 32; ++it) {
    const int id = (it << 8) + tid;
    const int lc = id >> 5;
    const int g = id & 31;
    const int gcol = ((lc >> 6) << 8) + (q << 6) + (lc & 63);
    stage[(lc << 5) | (g ^ (lc & 31))] = *((const float4*)(whh + (size_t)gcol * 256) + g);
  }
  __syncthreads();
  float4 wv[64];
#pragma unroll
  for (int g = 0; g < 32; ++g)
    wv[g] = stage[(tid << 5) | (g ^ (tid & 31))];
  __syncthreads();
  for (int it = 0; it < 32; ++it) {
    const int id = (it << 8) + tid;
    const int lc = id >> 5;
    const int g = id & 31;
    const int gcol = ((lc >> 6) << 8) + (q << 6) + (lc & 63);
    stage[(lc << 5) | (g ^ (lc & 31))] = *((const float4*)(whh + (size_t)gcol * 256) + 32 + g);
  }
  __syncthreads();
#pragma unroll
  for (int g = 0; g < 32; ++g)
    wv[32 + g] = stage[(tid << 5) | (g ^ (tid & 31))];

  hbuf[0][tid] = 0.0f;
  hbuf[1][tid] = 0.0f;
  float c_reg = 0.0f;
  const int sfirst = dir ? (SEQ - 1) : 0;
  float p = pre[((size_t)(sfirst * BATCH) + b) * 1024 + col];
  __syncthreads();

  for (int t = 0; t < SEQ; ++t) {
    const int s = dir ? (SEQ - 1 - t) : t;
    float np = 0.0f;
    if (t + 1 < SEQ) {
      const int sn = dir ? (s - 1) : (s + 1);
      np = pre[((size_t)(sn * BATCH) + b) * 1024 + col];
    }
    if (t > 0) {
      if (tid < 192) {
        const int pq = (q + 1 + (tid >> 6)) & 3;
        const int slot = (pq << 6) + (tid & 63);
        const float ef = 2.0f * (float)((t - 1) & 3);
        const float* addr = hx_w + ((t - 1) & 1) * 256 + slot;
        float v;
        int spin = 0;
        while (true) {
          if (spin < 16) {
            asm volatile("global_load_dword %0, %1, off sc0\n\t"
                         "s_waitcnt vmcnt(0)"
                         : "=v"(v) : "v"(addr));
          } else {
            v = __hip_atomic_load(addr, __ATOMIC_RELAXED, __HIP_MEMORY_SCOPE_AGENT);
          }
          if (__builtin_fabsf(v - ef) <= 1.0f) break;
          ++spin;
          if (spin > 4) __builtin_amdgcn_s_sleep(1);
        }
        hbuf[t & 1][slot] = v - ef;
      }
      __syncthreads();
    }
    float a0 = p, a1 = 0.f, a2 = 0.f, a3 = 0.f;
    const float4* hb = (const float4*)hbuf[t & 1];
#pragma unroll
    for (int g = 0; g < 64; ++g) {
      const float4 h4 = hb[g];
      a0 = fmaf(h4.x, wv[g].x, a0);
      a1 = fmaf(h4.y, wv[g].y, a1);
      a2 = fmaf(h4.z, wv[g].z, a2);
      a3 = fmaf(h4.w, wv[g].w, a3);
    }
    zbuf[tid] = (a0 + a1) + (a2 + a3);
    __syncthreads();
    if (tid < 64) {
      const float zi = zbuf[u];
      const float zf = zbuf[64 + u];
      const float zg = zbuf[128 + u];
      const float zo = zbuf[192 + u];
      c_reg = sigm(zf) * c_reg + sigm(zi) * tanh_fast(zg);
      const float h = sigm(zo) * tanh_fast(c_reg);
      __hip_atomic_store(hx_w + (t & 1) * 256 + (q << 6) + u, h + 2.0f * (float)(t & 3),
                         __ATOMIC_RELAXED, __HIP_MEMORY_SCOPE_AGENT);
      hbuf[(t + 1) & 1][(q << 6) + u] = h;
      hs[((size_t)(s * BATCH) + b) * 512 + dir * 256 + (q << 6) + u] = h;
    }
    p = np;
  }
}

// ---------------- attention: per time-step s, scores over the batch dim ----------------
__global__ __launch_bounds__(256) void attention_kernel(const float* __restrict__ h1s,
                                                        float* __restrict__ att) {
  const int s = blockIdx.x;
  __shared__ float wl[32][512];
  __shared__ float xT[512][36];
  __shared__ float sc[32][33];
  const int tid = threadIdx.x;
#pragma unroll
  for (int r = 0; r < 16; ++r) {
    int flat = r * 1024 + tid * 4;
    int bb = flat >> 9;
    int d = flat & 511;
    float4 wv = *(const float4*)(att + ((size_t)(s * BATCH) + bb) * 1024 + d);
    *(float4*)&wl[bb][d] = wv;
    float4 xv = *(const float4*)(h1s + ((size_t)(s * BATCH) + bb) * 512 + d);
    xT[d + 0][bb] = xv.x; xT[d + 1][bb] = xv.y; xT[d + 2][bb] = xv.z; xT[d + 3][bb] = xv.w;
  }
  __syncthreads();
  {
    const int i = tid >> 3;
    const int j0 = (tid & 7) << 2;
    float a0 = 0.f, a1 = 0.f, a2 = 0.f, a3 = 0.f;
    for (int k = 0; k < 512; ++k) {
      float wv = wl[i][k];
      float4 x4 = *(const float4*)&xT[k][j0];
      a0 += wv * x4.x; a1 += wv * x4.y; a2 += wv * x4.z; a3 += wv * x4.w;
    }
    sc[i][j0 + 0] = a0; sc[i][j0 + 1] = a1; sc[i][j0 + 2] = a2; sc[i][j0 + 3] = a3;
  }
  __syncthreads();
  if (tid < 32) {
    float m = -3.4e38f;
    for (int j = 0; j < 32; ++j) m = fmaxf(m, sc[tid][j]);
    float sum = 0.f;
    for (int j = 0; j < 32; ++j) { float ev = __expf(sc[tid][j] - m); sc[tid][j] = ev; sum += ev; }
    float inv = 1.0f / sum;
    for (int j = 0; j < 32; ++j) sc[tid][j] *= inv;
  }
  __syncthreads();
  {
    const int i = tid >> 3;
    const int dq = tid & 7;
#pragma unroll
    for (int rep = 0; rep < 8; ++rep) {
      const int d0 = dq * 64 + rep * 8;
      float g0 = 0.f, g1 = 0.f, g2 = 0.f, g3 = 0.f, g4 = 0.f, g5 = 0.f, g6 = 0.f, g7 = 0.f;
      for (int j = 0; j < 32; ++j) {
        float wt = sc[i][j];
        g0 += wt * xT[d0 + 0][j]; g1 += wt * xT[d0 + 1][j];
        g2 += wt * xT[d0 + 2][j]; g3 += wt * xT[d0 + 3][j];
        g4 += wt * xT[d0 + 4][j]; g5 += wt * xT[d0 + 5][j];
        g6 += wt * xT[d0 + 6][j]; g7 += wt * xT[d0 + 7][j];
      }
      float* o = att + ((size_t)(s * BATCH) + i) * 1024 + 512 + d0;
      *(float4*)(o) = make_float4(g0, g1, g2, g3);
      *(float4*)(o + 4) = make_float4(g4, g5, g6, g7);
    }
  }
}

// ---------------- Viterbi decode: one block per batch element ----------------
__global__ __launch_bounds__(64) void viterbi_kernel(const float* __restrict__ feats,
                                                     const float* __restrict__ trans,
                                                     int* __restrict__ out) {
  const int b = blockIdx.x;
  __shared__ float tl[NTAG][NTAG];
  __shared__ float fv[2][NTAG];
  __shared__ unsigned char bp[SEQ][NTAG];
  const int tid = threadIdx.x;
  for (int i = tid; i < NTAG * NTAG; i += 64) tl[i / NTAG][i % NTAG] = trans[i];
  if (tid < NTAG) fv[0][tid] = (tid == 10) ? 0.f : -10000.f;
  __syncthreads();
  for (int t = 0; t < SEQ; ++t) {
    const int cur = t & 1;
    if (tid < NTAG) {
      float m = -3.4e38f;
      int arg = 0;
      for (int p = 0; p < NTAG; ++p) {
        float v = fv[cur][p] + tl[tid][p];
        if (v > m) { m = v; arg = p; }   // strict > == first-max (matches jnp.argmax)
      }
      bp[t][tid] = (unsigned char)arg;
      fv[cur ^ 1][tid] = m + feats[((size_t)t * BATCH + b) * NTAG + tid];
    }
    __syncthreads();
  }
  if (tid == 0) {
    float m = -3.4e38f;
    int tag = 0;
    for (int p = 0; p < NTAG; ++p) {
      float v = fv[0][p] + tl[STOP_TAG][p];
      if (v > m) { m = v; tag = p; }
    }
    for (int t = SEQ - 1; t >= 0; --t) {
      out[b * SEQ + t] = tag;
      tag = bp[t][tag];
    }
  }
}

// ---------------- launch ----------------
extern "C" void kernel_launch(void* const* d_in, const int* in_sizes, int n_in,
                              void* d_out, int out_size, void* d_ws, size_t ws_size,
                              hipStream_t stream) {
  const int* inputs = (const int*)d_in[0];
  const float* emb = (const float*)d_in[1];
  const float* w1f_ih = (const float*)d_in[2];
  const float* w1f_hh = (const float*)d_in[3];
  const float* b1f_ih = (const float*)d_in[4];
  const float* b1f_hh = (const float*)d_in[5];
  const float* w1b_ih = (const float*)d_in[6];
  const float* w1b_hh = (const float*)d_in[7];
  const float* b1b_ih = (const float*)d_in[8];
  const float* b1b_hh = (const float*)d_in[9];
  const float* attW = (const float*)d_in[10];
  const float* w2f_ih = (const float*)d_in[11];
  const float* w2f_hh = (const float*)d_in[12];
  const float* b2f_ih = (const float*)d_in[13];
  const float* b2f_hh = (const float*)d_in[14];
  const float* w2b_ih = (const float*)d_in[15];
  const float* w2b_hh = (const float*)d_in[16];
  const float* b2b_ih = (const float*)d_in[17];
  const float* b2b_hh = (const float*)d_in[18];
  const float* h2t_W = (const float*)d_in[19];
  const float* h2t_b = (const float*)d_in[20];
  const float* trans = (const float*)d_in[21];

  // Memory plan (footprint identical to R14/R16; all regions < 62,980,608 f):
  //   preF: L1 pre fwd -> (dead) h1h/h1l -> MFMA L2 #1 output
  //   preB: L1 pre bwd -> (dead) attl
  //   h1s : x0h/x0l -> (scan1 overwrites) h1 -> (dead after attention) atth -> h2s
  //   att : w1 hi/lo -> attW-GEMM output [w] + attention [g] -> (dead) L2 #2 output
  //   x0  : embeddings -> (dead) attWh/attWl -> w2 hi/lo -> feats
  float* ws = (float*)d_ws;
  float* preF = ws;                         // 16,777,216 f
  float* preB = ws + 16777216;              // 16,777,216 f
  float* h1s  = ws + 33554432;              //  8,388,608 f
  float* att  = ws + 41943040;              // 16,777,216 f
  float* x0   = ws + 58720256;              //  4,194,304 f
  float* feats = x0;
  float* hx1  = ws + 62914560;              // 32,768 f
  float* hx2  = ws + 62947328;              // 32,768 f
  unsigned int* claim1 = (unsigned int*)(ws + 62980096);  // 256 u
  unsigned int* claim2 = (unsigned int*)(ws + 62980352);  // 256 u
  // L1 operands:
  ushort* x0h  = (ushort*)h1s;                    // 4,194,304 us
  ushort* x0l  = (ushort*)(h1s + 2097152);        // 4,194,304 us
  ushort* w1fh = (ushort*)att;                    // 262,144 us each
  ushort* w1fl = (ushort*)(att + 131072);
  ushort* w1bh = (ushort*)(att + 262144);
  ushort* w1bl = (ushort*)(att + 393216);
  // attW-GEMM operands:
  ushort* h1h  = (ushort*)preF;                   // 8,388,608 us
  ushort* h1l  = (ushort*)(preF + 4194304);       // 8,388,608 us
  ushort* attWh = (ushort*)x0;                    // 262,144 us each
  ushort* attWl = (ushort*)(x0 + 131072);
  // L2 operands:
  ushort* atth = (ushort*)h1s;                    // 16,777,216 us
  ushort* attl = (ushort*)preB;                   // 16,777,216 us
  ushort* w2fh = (ushort*)x0;                     // 1,048,576 us each
  ushort* w2fl = (ushort*)(x0 + 524288);
  ushort* w2bh = (ushort*)(x0 + 1048576);
  ushort* w2bl = (ushort*)(x0 + 1572864);
  float* preB2 = att;                             // L2 #2 output region
  int* out = (int*)d_out;

  hipMemsetAsync(hx1, 0xFF, 2 * 32768 * sizeof(float), stream);
  hipMemsetAsync(claim1, 0, 2 * 256 * sizeof(unsigned int), stream);
  embed_kernel<<<SEQ * BATCH, 64, 0, stream>>>(inputs, emb, x0);
  // L1 pre-GEMMs on MFMA
  cvt_hilo<<<2048, 256, 0, stream>>>(x0, x0h, x0l, 1048576);
  cvt_hilo<<<256, 256, 0, stream>>>(w1f_ih, w1fh, w1fl, 65536);
  cvt_hilo<<<256, 256, 0, stream>>>(w1b_ih, w1bh, w1bl, 65536);
  gemm_mfma<<<dim3(128, 8), 256, 0, stream>>>(x0h, x0l, w1fh, w1fl, b1f_ih, b1f_hh, preF, 16384, 1024, 256, 1024);
  gemm_mfma<<<dim3(128, 8), 256, 0, stream>>>(x0h, x0l, w1bh, w1bl, b1b_ih, b1b_hh, preB, 16384, 1024, 256, 1024);
  lstm_scan<<<256, 256, 0, stream>>>(preF, preB, w1f_hh, w1b_hh, h1s, hx1, claim1);
  // attW GEMM on MFMA (preF, x0 dead -> h1 hi/lo, attW hi/lo)
  cvt_hilo<<<4096, 256, 0, stream>>>(h1s, h1h, h1l, 2097152);
  cvt_hilo<<<256, 256, 0, stream>>>(attW, attWh, attWl, 65536);
  gemm_mfma<<<dim3(128, 4), 256, 0, stream>>>(h1h, h1l, attWh, attWl, nullptr, nullptr, att, 16384, 512, 512, 1024);
  attention_kernel<<<SEQ, 256, 0, stream>>>(h1s, att);
  // L2 pre-GEMMs on MFMA (h1s, preB, x0 dead -> att hi/lo, w2 hi/lo)
  cvt_hilo<<<4096, 256, 0, stream>>>(att, atth, attl, 4194304);
  cvt_hilo<<<512, 256, 0, stream>>>(w2f_ih, w2fh, w2fl, 262144);
  cvt_hilo<<<512, 256, 0, stream>>>(w2b_ih, w2bh, w2bl, 262144);
  gemm_mfma<<<dim3(128, 8), 256, 0, stream>>>(atth, attl, w2fh, w2fl, b2f_ih, b2f_hh, preF, 16384, 1024, 1024, 1024);
  gemm_mfma<<<dim3(128, 8), 256, 0, stream>>>(atth, attl, w2bh, w2bl, b2b_ih, b2b_hh, preB2, 16384, 1024, 1024, 1024);
  lstm_scan<<<256, 256, 0, stream>>>(preF, preB2, w2f_hh, w2b_hh, h1s, hx2, claim2);
  gemm_nt<<<dim3(256, 1), 256, 0, stream>>>(h1s, h2t_W, h2t_b, nullptr, feats, 16384, 12, 512, 12);
  viterbi_kernel<<<BATCH, 64, 0, stream>>>(feats, trans, out);
}